// Round 1
// baseline (2746.148 us; speedup 1.0000x reference)
//
#include <hip/hip_runtime.h>
#include <cstdint>
#include <cstddef>

#define NN 100000
#define NEDGE 800000

// ---------------- degree + norm ----------------

__global__ void deg_kernel(const int* __restrict__ src, const int* __restrict__ dst,
                           int* __restrict__ dOut, int* __restrict__ dIn, int E) {
    int i = blockIdx.x * blockDim.x + threadIdx.x;
    if (i < E) {
        atomicAdd(&dOut[src[i]], 1);
        atomicAdd(&dIn[dst[i]], 1);
    }
}

__global__ void norm_kernel(const int* __restrict__ dOut, const int* __restrict__ dIn,
                            float* __restrict__ ns, float* __restrict__ nd, int n) {
    int i = blockIdx.x * blockDim.x + threadIdx.x;
    if (i < n) {
        int a = dOut[i] > 1 ? dOut[i] : 1;
        int b = dIn[i] > 1 ? dIn[i] : 1;
        ns[i] = 1.0f / sqrtf((float)a);
        nd[i] = 1.0f / sqrtf((float)b);
    }
}

// ---------------- dense GEMM: C = rowscale(A @ W, s) ----------------
// A: [n,K] row-major, W: [K,Dout] row-major, C: [n,Dout].
// 64x64 tile per 256-thread block, 4x4 micro-tile per thread, BK=16.

__global__ __launch_bounds__(256) void gemm_rowscale(
        const float* __restrict__ A, const float* __restrict__ W,
        const float* __restrict__ s, float* __restrict__ C,
        int n, int K, int Dout) {
    __shared__ float As[16][64];
    __shared__ float Bs[16][68];
    const int tid = threadIdx.x;
    const int tx = tid & 15;
    const int ty = tid >> 4;
    const int row0 = blockIdx.x * 64;
    const int col0 = blockIdx.y * 64;
    float acc[4][4] = {};

    for (int k0 = 0; k0 < K; k0 += 16) {
        #pragma unroll
        for (int i = 0; i < 4; i++) {
            int lin = tid + i * 256;
            int r = lin >> 4, kk = lin & 15;
            int row = row0 + r;
            As[kk][r] = (row < n) ? A[(size_t)row * K + (k0 + kk)] : 0.0f;
        }
        #pragma unroll
        for (int i = 0; i < 4; i++) {
            int lin = tid + i * 256;
            int kk = lin >> 6, c = lin & 63;
            Bs[kk][c] = W[(size_t)(k0 + kk) * Dout + (col0 + c)];
        }
        __syncthreads();
        #pragma unroll
        for (int kk = 0; kk < 16; kk++) {
            float a[4], bb[4];
            #pragma unroll
            for (int i = 0; i < 4; i++) a[i] = As[kk][ty * 4 + i];
            #pragma unroll
            for (int j = 0; j < 4; j++) bb[j] = Bs[kk][tx * 4 + j];
            #pragma unroll
            for (int i = 0; i < 4; i++)
                #pragma unroll
                for (int j = 0; j < 4; j++)
                    acc[i][j] = fmaf(a[i], bb[j], acc[i][j]);
        }
        __syncthreads();
    }

    #pragma unroll
    for (int i = 0; i < 4; i++) {
        int row = row0 + ty * 4 + i;
        if (row < n) {
            float sc = s[row];
            #pragma unroll
            for (int j = 0; j < 4; j++)
                C[(size_t)row * Dout + (col0 + tx * 4 + j)] = acc[i][j] * sc;
        }
    }
}

// ---------------- SpMM: agg[dst] += h[src] (atomic, edge-parallel) ----------------

__global__ void spmm_kernel(const float* __restrict__ h, const int* __restrict__ src,
                            const int* __restrict__ dst, float* __restrict__ agg,
                            int E, int logD) {
    long long idx = (long long)blockIdx.x * blockDim.x + threadIdx.x;
    long long total = (long long)E << logD;
    if (idx < total) {
        int e = (int)(idx >> logD);
        int f = (int)(idx & ((1 << logD) - 1));
        int se = src[e];
        int de = dst[e];
        atomicAdd(&agg[((size_t)de << logD) + f], h[((size_t)se << logD) + f]);
    }
}

// ---------------- epilogue: out = relu(agg * nd[node] + bias[f]) ----------------

__global__ void epi_kernel(const float* __restrict__ agg, const float* __restrict__ nd,
                           const float* __restrict__ bias, float* __restrict__ out,
                           int n, int logD) {
    long long idx = (long long)blockIdx.x * blockDim.x + threadIdx.x;
    long long total = (long long)n << logD;
    if (idx < total) {
        int node = (int)(idx >> logD);
        int f = (int)(idx & ((1 << logD) - 1));
        float v = agg[idx] * nd[node] + bias[f];
        out[idx] = v > 0.0f ? v : 0.0f;
    }
}

// ---------------- classifier: out = h @ Wc + bc   (Dout = 4, K = 256) ----------------

__global__ __launch_bounds__(256) void classifier_kernel(
        const float* __restrict__ h, const float* __restrict__ Wc,
        const float* __restrict__ bc, float* __restrict__ out, int n) {
    __shared__ float Ws[256 * 4];
    int tid = threadIdx.x;
    for (int i = tid; i < 1024; i += 256) Ws[i] = Wc[i];
    __syncthreads();
    int node = blockIdx.x * 64 + (tid >> 2);
    int c = tid & 3;
    if (node < n) {
        float sum = bc[c];
        const float* hr = h + (size_t)node * 256;
        #pragma unroll 8
        for (int k = 0; k < 256; k++)
            sum = fmaf(hr[k], Ws[k * 4 + c], sum);
        out[(size_t)node * 4 + c] = sum;
    }
}

// ---------------- launch ----------------

extern "C" void kernel_launch(void* const* d_in, const int* in_sizes, int n_in,
                              void* d_out, int out_size, void* d_ws, size_t ws_size,
                              hipStream_t stream) {
    const float* x   = (const float*)d_in[0];
    const int*   src = (const int*)d_in[1];
    const int*   dst = (const int*)d_in[2];
    const float* W[4] = {(const float*)d_in[3], (const float*)d_in[5],
                         (const float*)d_in[7], (const float*)d_in[9]};
    const float* b[4] = {(const float*)d_in[4], (const float*)d_in[6],
                         (const float*)d_in[8], (const float*)d_in[10]};
    const float* Wc = (const float*)d_in[11];
    const float* bc = (const float*)d_in[12];
    float* out = (float*)d_out;

    // workspace layout
    float* bufA = (float*)d_ws;                         // N*256 f32
    float* bufB = bufA + (size_t)NN * 256;              // N*256 f32
    int*   degO = (int*)(bufB + (size_t)NN * 256);      // N int
    int*   degI = degO + NN;                            // N int
    float* ns   = (float*)(degI + NN);                  // N f32
    float* nd   = ns + NN;                              // N f32
    (void)in_sizes; (void)n_in; (void)out_size; (void)ws_size;

    // degrees + norms
    hipMemsetAsync(degO, 0, 2 * (size_t)NN * sizeof(int), stream);
    deg_kernel<<<(NEDGE + 255) / 256, 256, 0, stream>>>(src, dst, degO, degI, NEDGE);
    norm_kernel<<<(NN + 255) / 256, 256, 0, stream>>>(degO, degI, ns, nd, NN);

    const int dims[5] = {128, 128, 128, 256, 256};
    float* bufs[2] = {bufA, bufB};
    const float* cur = x;

    for (int l = 0; l < 4; l++) {
        int K = dims[l], Dout = dims[l + 1];
        int logD = (Dout == 128) ? 7 : 8;
        float* G   = bufs[l & 1];          // gemm output
        float* AGG = bufs[(l + 1) & 1];    // aggregation buffer (== cur's buffer for l>=1; safe: stream-ordered)

        dim3 ggrid((NN + 63) / 64, Dout / 64);
        gemm_rowscale<<<ggrid, 256, 0, stream>>>(cur, W[l], ns, G, NN, K, Dout);

        hipMemsetAsync(AGG, 0, (size_t)NN * Dout * sizeof(float), stream);

        long long totalE = (long long)NEDGE << logD;
        spmm_kernel<<<(unsigned)((totalE + 255) / 256), 256, 0, stream>>>(G, src, dst, AGG, NEDGE, logD);

        long long totalN = (long long)NN << logD;
        epi_kernel<<<(unsigned)((totalN + 255) / 256), 256, 0, stream>>>(AGG, nd, b[l], G, NN, logD);

        cur = G;
    }

    classifier_kernel<<<(NN + 63) / 64, 256, 0, stream>>>(cur, Wc, bc, out, NN);
}

// Round 3
// 1029.298 us; speedup vs baseline: 2.6680x; 2.6680x over previous
//
#include <hip/hip_runtime.h>
#include <cstdint>
#include <cstddef>

#define NN 100000
#define NEDGE 800000
#define SCAN_CHUNK 2048

// ---------------- degree ----------------

__global__ void deg_kernel(const int* __restrict__ src, const int* __restrict__ dst,
                           int* __restrict__ dOut, int* __restrict__ dIn, int E) {
    int i = blockIdx.x * blockDim.x + threadIdx.x;
    if (i < E) {
        atomicAdd(&dOut[src[i]], 1);
        atomicAdd(&dIn[dst[i]], 1);
    }
}

__global__ void norm_kernel(const int* __restrict__ dOut, const int* __restrict__ dIn,
                            float* __restrict__ ns, float* __restrict__ nd, int n) {
    int i = blockIdx.x * blockDim.x + threadIdx.x;
    if (i < n) {
        int a = dOut[i] > 1 ? dOut[i] : 1;
        int b = dIn[i] > 1 ? dIn[i] : 1;
        ns[i] = 1.0f / sqrtf((float)a);
        nd[i] = 1.0f / sqrtf((float)b);
    }
}

// ---------------- exclusive scan of in-degrees -> rowptr ----------------

__global__ void scan_reduce(const int* __restrict__ deg, int* __restrict__ bsum, int n) {
    __shared__ int sdata[256];
    int b = blockIdx.x, t = threadIdx.x;
    int base = b * SCAN_CHUNK;
    int sum = 0;
    for (int i = t; i < SCAN_CHUNK; i += 256) {
        int idx = base + i;
        if (idx < n) sum += deg[idx];
    }
    sdata[t] = sum;
    __syncthreads();
    for (int s = 128; s > 0; s >>= 1) {
        if (t < s) sdata[t] += sdata[t + s];
        __syncthreads();
    }
    if (t == 0) bsum[b] = sdata[0];
}

__global__ void scan_bsums(int* bsum, int nb) {
    if (threadIdx.x == 0 && blockIdx.x == 0) {
        int acc = 0;
        for (int i = 0; i < nb; i++) { int v = bsum[i]; bsum[i] = acc; acc += v; }
    }
}

__global__ void scan_final(const int* __restrict__ deg, const int* __restrict__ bsum,
                           int* __restrict__ rowptr, int n, int E) {
    __shared__ int tsum[256];
    int b = blockIdx.x, t = threadIdx.x;
    int base = b * SCAN_CHUNK;
    int loc[8];
    int s = 0;
    #pragma unroll
    for (int i = 0; i < 8; i++) {
        int idx = base + t * 8 + i;
        loc[i] = s;
        s += (idx < n) ? deg[idx] : 0;
    }
    tsum[t] = s;
    __syncthreads();
    for (int off = 1; off < 256; off <<= 1) {
        int v = (t >= off) ? tsum[t - off] : 0;
        __syncthreads();
        tsum[t] += v;
        __syncthreads();
    }
    int prefix = bsum[b] + (t > 0 ? tsum[t - 1] : 0);
    #pragma unroll
    for (int i = 0; i < 8; i++) {
        int idx = base + t * 8 + i;
        if (idx < n) rowptr[idx] = prefix + loc[i];
    }
    if (b == 0 && t == 0) rowptr[n] = E;
}

__global__ void copy_int(const int* __restrict__ a, int* __restrict__ b, int n) {
    int i = blockIdx.x * blockDim.x + threadIdx.x;
    if (i < n) b[i] = a[i];
}

// ---------------- scatter edges into CSR (src ids, grouped by dst) ----------------

__global__ void scatter_kernel(const int* __restrict__ src, const int* __restrict__ dst,
                               int* __restrict__ cursor, int* __restrict__ permSrc, int E) {
    int i = blockIdx.x * blockDim.x + threadIdx.x;
    if (i < E) {
        int p = atomicAdd(&cursor[dst[i]], 1);
        permSrc[p] = src[i];
    }
}

// ---------------- dense GEMM: C = rowscale(A @ W, s) ----------------

__global__ __launch_bounds__(256) void gemm_rowscale(
        const float* __restrict__ A, const float* __restrict__ W,
        const float* __restrict__ s, float* __restrict__ C,
        int n, int K, int Dout) {
    __shared__ float As[16][64];
    __shared__ float Bs[16][68];
    const int tid = threadIdx.x;
    const int tx = tid & 15;
    const int ty = tid >> 4;
    const int row0 = blockIdx.x * 64;
    const int col0 = blockIdx.y * 64;
    float acc[4][4] = {};

    for (int k0 = 0; k0 < K; k0 += 16) {
        #pragma unroll
        for (int i = 0; i < 4; i++) {
            int lin = tid + i * 256;
            int r = lin >> 4, kk = lin & 15;
            int row = row0 + r;
            As[kk][r] = (row < n) ? A[(size_t)row * K + (k0 + kk)] : 0.0f;
        }
        #pragma unroll
        for (int i = 0; i < 4; i++) {
            int lin = tid + i * 256;
            int kk = lin >> 6, c = lin & 63;
            Bs[kk][c] = W[(size_t)(k0 + kk) * Dout + (col0 + c)];
        }
        __syncthreads();
        #pragma unroll
        for (int kk = 0; kk < 16; kk++) {
            float a[4], bb[4];
            #pragma unroll
            for (int i = 0; i < 4; i++) a[i] = As[kk][ty * 4 + i];
            #pragma unroll
            for (int j = 0; j < 4; j++) bb[j] = Bs[kk][tx * 4 + j];
            #pragma unroll
            for (int i = 0; i < 4; i++)
                #pragma unroll
                for (int j = 0; j < 4; j++)
                    acc[i][j] = fmaf(a[i], bb[j], acc[i][j]);
        }
        __syncthreads();
    }

    #pragma unroll
    for (int i = 0; i < 4; i++) {
        int row = row0 + ty * 4 + i;
        if (row < n) {
            float sc = s[row];
            #pragma unroll
            for (int j = 0; j < 4; j++)
                C[(size_t)row * Dout + (col0 + tx * 4 + j)] = acc[i][j] * sc;
        }
    }
}

// ---------------- fused CSR aggregation + norm + bias + relu ----------------
// One wave (64 lanes) per destination node; lane covers D/64 features.

template<int D>
__global__ __launch_bounds__(256) void agg_kernel(
        const float* __restrict__ h, const int* __restrict__ rowptr,
        const int* __restrict__ permSrc, const float* __restrict__ nd,
        const float* __restrict__ bias, float* __restrict__ out, int n) {
    int node = blockIdx.x * 4 + (threadIdx.x >> 6);
    if (node >= n) return;
    int lane = threadIdx.x & 63;
    constexpr int V = D / 64;  // 2 or 4
    float acc[V];
    #pragma unroll
    for (int j = 0; j < V; j++) acc[j] = 0.0f;
    const int f0 = lane * V;
    int r0 = rowptr[node], r1 = rowptr[node + 1];
    for (int e = r0; e < r1; e++) {
        int sidx = permSrc[e];
        const float* hp = h + (size_t)sidx * D + f0;
        if constexpr (V == 4) {
            float4 v = *reinterpret_cast<const float4*>(hp);
            acc[0] += v.x; acc[1] += v.y; acc[2] += v.z; acc[3] += v.w;
        } else {
            float2 v = *reinterpret_cast<const float2*>(hp);
            acc[0] += v.x; acc[1] += v.y;
        }
    }
    float sc = nd[node];
    float* op = out + (size_t)node * D + f0;
    if constexpr (V == 4) {
        float4 r;
        r.x = fmaxf(acc[0] * sc + bias[f0 + 0], 0.0f);
        r.y = fmaxf(acc[1] * sc + bias[f0 + 1], 0.0f);
        r.z = fmaxf(acc[2] * sc + bias[f0 + 2], 0.0f);
        r.w = fmaxf(acc[3] * sc + bias[f0 + 3], 0.0f);
        *reinterpret_cast<float4*>(op) = r;
    } else {
        float2 r;
        r.x = fmaxf(acc[0] * sc + bias[f0 + 0], 0.0f);
        r.y = fmaxf(acc[1] * sc + bias[f0 + 1], 0.0f);
        *reinterpret_cast<float2*>(op) = r;
    }
}

// ---------------- classifier: out = h @ Wc + bc   (Dout = 4, K = 256) ----------------

__global__ __launch_bounds__(256) void classifier_kernel(
        const float* __restrict__ h, const float* __restrict__ Wc,
        const float* __restrict__ bc, float* __restrict__ out, int n) {
    __shared__ float Ws[256 * 4];
    int tid = threadIdx.x;
    for (int i = tid; i < 1024; i += 256) Ws[i] = Wc[i];
    __syncthreads();
    int node = blockIdx.x * 64 + (tid >> 2);
    int c = tid & 3;
    if (node < n) {
        float sum = bc[c];
        const float* hr = h + (size_t)node * 256;
        #pragma unroll 8
        for (int k = 0; k < 256; k++)
            sum = fmaf(hr[k], Ws[k * 4 + c], sum);
        out[(size_t)node * 4 + c] = sum;
    }
}

// ---------------- launch ----------------

extern "C" void kernel_launch(void* const* d_in, const int* in_sizes, int n_in,
                              void* d_out, int out_size, void* d_ws, size_t ws_size,
                              hipStream_t stream) {
    const float* x   = (const float*)d_in[0];
    const int*   src = (const int*)d_in[1];
    const int*   dst = (const int*)d_in[2];
    const float* W[4] = {(const float*)d_in[3], (const float*)d_in[5],
                         (const float*)d_in[7], (const float*)d_in[9]};
    const float* b[4] = {(const float*)d_in[4], (const float*)d_in[6],
                         (const float*)d_in[8], (const float*)d_in[10]};
    const float* Wc = (const float*)d_in[11];
    const float* bc = (const float*)d_in[12];
    float* out = (float*)d_out;

    // persistent workspace layout
    float* bufA    = (float*)d_ws;                          // N*256 f32  (GEMM output, every layer)
    float* bufB    = bufA + (size_t)NN * 256;               // N*256 f32  (agg output / next input)
    float* ns      = bufB + (size_t)NN * 256;               // N f32
    float* nd      = ns + NN;                               // N f32
    int*   rowptr  = (int*)(nd + NN);                       // N+1 int
    int*   permSrc = rowptr + (NN + 1);                     // E int
    // transient (consumed before the first GEMM writes bufA): alias into bufA
    int*   degO   = (int*)bufA;                             // N int
    int*   degI   = degO + NN;                              // N int
    int*   cursor = degI + NN;                              // N int
    int*   bsum   = cursor + NN;                            // 64 int
    (void)in_sizes; (void)n_in; (void)out_size; (void)ws_size;

    const int NB = (NN + SCAN_CHUNK - 1) / SCAN_CHUNK;

    // degrees + norms
    hipMemsetAsync(degO, 0, 2 * (size_t)NN * sizeof(int), stream);
    deg_kernel<<<(NEDGE + 255) / 256, 256, 0, stream>>>(src, dst, degO, degI, NEDGE);
    norm_kernel<<<(NN + 255) / 256, 256, 0, stream>>>(degO, degI, ns, nd, NN);

    // CSR build: rowptr = exclusive_scan(degI); scatter src ids grouped by dst
    scan_reduce<<<NB, 256, 0, stream>>>(degI, bsum, NN);
    scan_bsums<<<1, 64, 0, stream>>>(bsum, NB);
    scan_final<<<NB, 256, 0, stream>>>(degI, bsum, rowptr, NN, NEDGE);
    copy_int<<<(NN + 255) / 256, 256, 0, stream>>>(rowptr, cursor, NN);
    scatter_kernel<<<(NEDGE + 255) / 256, 256, 0, stream>>>(src, dst, cursor, permSrc, NEDGE);

    const int dims[5] = {128, 128, 128, 256, 256};
    const float* cur = x;

    // Fixed roles: GEMM always writes bufA, aggregation always writes bufB.
    // gemm(cur -> bufA); agg(bufA -> bufB); cur = bufB.  No buffer is ever
    // read and written by the same kernel (stream order covers reuse of cur).
    for (int l = 0; l < 4; l++) {
        int K = dims[l], Dout = dims[l + 1];
        float* G    = bufA;
        float* AOUT = bufB;

        dim3 ggrid((NN + 63) / 64, Dout / 64);
        gemm_rowscale<<<ggrid, 256, 0, stream>>>(cur, W[l], ns, G, NN, K, Dout);

        int ablocks = (NN + 3) / 4;
        if (Dout == 128)
            agg_kernel<128><<<ablocks, 256, 0, stream>>>(G, rowptr, permSrc, nd, b[l], AOUT, NN);
        else
            agg_kernel<256><<<ablocks, 256, 0, stream>>>(G, rowptr, permSrc, nd, b[l], AOUT, NN);

        cur = AOUT;
    }

    classifier_kernel<<<(NN + 63) / 64, 256, 0, stream>>>(cur, Wc, bc, out, NN);
}

// Round 4
// 824.327 us; speedup vs baseline: 3.3314x; 1.2487x over previous
//
#include <hip/hip_runtime.h>
#include <cstdint>
#include <cstddef>

#define NN 100000
#define NEDGE 800000
#define SCAN_CHUNK 2048

typedef __attribute__((ext_vector_type(8))) short short8v;
typedef __attribute__((ext_vector_type(16))) float float16v;

__device__ inline ushort f2bf(float f) {
    uint32_t u = __float_as_uint(f);
    u += 0x7fff + ((u >> 16) & 1);   // round-to-nearest-even
    return (ushort)(u >> 16);
}
__device__ inline float bf2f(ushort h) { return __uint_as_float(((uint32_t)h) << 16); }
__device__ inline void split2(float a, ushort& h, ushort& l) {
    h = f2bf(a);
    l = f2bf(a - bf2f(h));
}

// ---------------- degree + norm ----------------

__global__ void deg_kernel(const int* __restrict__ src, const int* __restrict__ dst,
                           int* __restrict__ dOut, int* __restrict__ dIn, int E) {
    int i = blockIdx.x * blockDim.x + threadIdx.x;
    if (i < E) {
        atomicAdd(&dOut[src[i]], 1);
        atomicAdd(&dIn[dst[i]], 1);
    }
}

__global__ void norm_kernel(const int* __restrict__ dOut, const int* __restrict__ dIn,
                            float* __restrict__ ns, float* __restrict__ nd, int n) {
    int i = blockIdx.x * blockDim.x + threadIdx.x;
    if (i < n) {
        int a = dOut[i] > 1 ? dOut[i] : 1;
        int b = dIn[i] > 1 ? dIn[i] : 1;
        ns[i] = 1.0f / sqrtf((float)a);
        nd[i] = 1.0f / sqrtf((float)b);
    }
}

// ---------------- exclusive scan of in-degrees -> rowptr ----------------

__global__ void scan_reduce(const int* __restrict__ deg, int* __restrict__ bsum, int n) {
    __shared__ int sdata[256];
    int b = blockIdx.x, t = threadIdx.x;
    int base = b * SCAN_CHUNK;
    int sum = 0;
    for (int i = t; i < SCAN_CHUNK; i += 256) {
        int idx = base + i;
        if (idx < n) sum += deg[idx];
    }
    sdata[t] = sum;
    __syncthreads();
    for (int s = 128; s > 0; s >>= 1) {
        if (t < s) sdata[t] += sdata[t + s];
        __syncthreads();
    }
    if (t == 0) bsum[b] = sdata[0];
}

__global__ void scan_bsums(int* bsum, int nb) {
    if (threadIdx.x == 0 && blockIdx.x == 0) {
        int acc = 0;
        for (int i = 0; i < nb; i++) { int v = bsum[i]; bsum[i] = acc; acc += v; }
    }
}

__global__ void scan_final(const int* __restrict__ deg, const int* __restrict__ bsum,
                           int* __restrict__ rowptr, int n, int E) {
    __shared__ int tsum[256];
    int b = blockIdx.x, t = threadIdx.x;
    int base = b * SCAN_CHUNK;
    int loc[8];
    int s = 0;
    #pragma unroll
    for (int i = 0; i < 8; i++) {
        int idx = base + t * 8 + i;
        loc[i] = s;
        s += (idx < n) ? deg[idx] : 0;
    }
    tsum[t] = s;
    __syncthreads();
    for (int off = 1; off < 256; off <<= 1) {
        int v = (t >= off) ? tsum[t - off] : 0;
        __syncthreads();
        tsum[t] += v;
        __syncthreads();
    }
    int prefix = bsum[b] + (t > 0 ? tsum[t - 1] : 0);
    #pragma unroll
    for (int i = 0; i < 8; i++) {
        int idx = base + t * 8 + i;
        if (idx < n) rowptr[idx] = prefix + loc[i];
    }
    if (b == 0 && t == 0) rowptr[n] = E;
}

__global__ void copy_int(const int* __restrict__ a, int* __restrict__ b, int n) {
    int i = blockIdx.x * blockDim.x + threadIdx.x;
    if (i < n) b[i] = a[i];
}

__global__ void scatter_kernel(const int* __restrict__ src, const int* __restrict__ dst,
                               int* __restrict__ cursor, int* __restrict__ permSrc, int E) {
    int i = blockIdx.x * blockDim.x + threadIdx.x;
    if (i < E) {
        int p = atomicAdd(&cursor[dst[i]], 1);
        permSrc[p] = src[i];
    }
}

// ---------------- converters ----------------
// x[N][128] * ns -> hi/lo bf16
__global__ void convx_kernel(const float* __restrict__ x, const float* __restrict__ ns,
                             ushort* __restrict__ Ah, ushort* __restrict__ Al, int n) {
    int idx = blockIdx.x * blockDim.x + threadIdx.x;   // float4 units
    if (idx >= n * 32) return;
    int node = idx >> 5;
    int f0 = (idx & 31) * 4;
    float sc = ns[node];
    float4 v = *reinterpret_cast<const float4*>(x + (size_t)node * 128 + f0);
    ushort4 h, l;
    split2(v.x * sc, h.x, l.x);
    split2(v.y * sc, h.y, l.y);
    split2(v.z * sc, h.z, l.z);
    split2(v.w * sc, h.w, l.w);
    *reinterpret_cast<ushort4*>(Ah + (size_t)node * 128 + f0) = h;
    *reinterpret_cast<ushort4*>(Al + (size_t)node * 128 + f0) = l;
}

// W[K][Dout] -> transposed hi/lo [Dout][K]
__global__ void convw_kernel(const float* __restrict__ W, ushort* __restrict__ Bh,
                             ushort* __restrict__ Bl, int K, int logD) {
    int idx = blockIdx.x * blockDim.x + threadIdx.x;
    if (idx >= (K << logD)) return;
    int k = idx >> logD;
    int d = idx & ((1 << logD) - 1);
    ushort h, l;
    split2(W[idx], h, l);
    Bh[(size_t)d * K + k] = h;
    Bl[(size_t)d * K + k] = l;
}

// ---------------- MFMA GEMM: C[n][Dout] = (Ahi+Alo)[n][K] @ (Bhi+Blo)^T[Dout][K] ----------------
// 64x64 tile, 4 waves in 2x2 quadrants of mfma_f32_32x32x16_bf16, K-step 64.
// Split product: Ah*Bh + Ah*Bl + Al*Bh (drop lo*lo): ~2^-16 relative error.

__global__ __launch_bounds__(256) void gemm_mfma(
        const ushort* __restrict__ Ahi, const ushort* __restrict__ Alo,
        const ushort* __restrict__ Bhi, const ushort* __restrict__ Blo,
        float* __restrict__ C, int n, int K, int Dout) {
    __shared__ __align__(16) ushort sAh[64][72];
    __shared__ __align__(16) ushort sAl[64][72];
    __shared__ __align__(16) ushort sBh[64][72];
    __shared__ __align__(16) ushort sBl[64][72];
    const int tid = threadIdx.x;
    const int row0 = blockIdx.x * 64;
    const int col0 = blockIdx.y * 64;
    const int lane = tid & 63;
    const int wid = tid >> 6;
    const int wr = (wid >> 1) * 32;   // wave's row quadrant
    const int wc = (wid & 1) * 32;    // wave's col quadrant
    const int l31 = lane & 31;
    const int kg = lane >> 5;         // k-group (0/1)

    // staging map: 512 16B-chunks per buffer, 2 per thread
    const int c1 = tid, c2 = tid + 256;
    const int r1 = c1 >> 3, ko1 = (c1 & 7) * 8;
    const int r2 = c2 >> 3, ko2 = (c2 & 7) * 8;
    const uint4 zero4 = make_uint4(0u, 0u, 0u, 0u);

    float16v acc = {0.f,0.f,0.f,0.f,0.f,0.f,0.f,0.f,0.f,0.f,0.f,0.f,0.f,0.f,0.f,0.f};

    for (int k0 = 0; k0 < K; k0 += 64) {
        // stage A (hi/lo) with row guard
        bool v1 = (row0 + r1) < n, v2 = (row0 + r2) < n;
        size_t ga1 = (size_t)(row0 + r1) * K + k0 + ko1;
        size_t ga2 = (size_t)(row0 + r2) * K + k0 + ko2;
        *reinterpret_cast<uint4*>(&sAh[r1][ko1]) = v1 ? *reinterpret_cast<const uint4*>(Ahi + ga1) : zero4;
        *reinterpret_cast<uint4*>(&sAh[r2][ko2]) = v2 ? *reinterpret_cast<const uint4*>(Ahi + ga2) : zero4;
        *reinterpret_cast<uint4*>(&sAl[r1][ko1]) = v1 ? *reinterpret_cast<const uint4*>(Alo + ga1) : zero4;
        *reinterpret_cast<uint4*>(&sAl[r2][ko2]) = v2 ? *reinterpret_cast<const uint4*>(Alo + ga2) : zero4;
        // stage B (hi/lo), always in bounds (Dout multiple of 64)
        size_t gb1 = (size_t)(col0 + r1) * K + k0 + ko1;
        size_t gb2 = (size_t)(col0 + r2) * K + k0 + ko2;
        *reinterpret_cast<uint4*>(&sBh[r1][ko1]) = *reinterpret_cast<const uint4*>(Bhi + gb1);
        *reinterpret_cast<uint4*>(&sBh[r2][ko2]) = *reinterpret_cast<const uint4*>(Bhi + gb2);
        *reinterpret_cast<uint4*>(&sBl[r1][ko1]) = *reinterpret_cast<const uint4*>(Blo + gb1);
        *reinterpret_cast<uint4*>(&sBl[r2][ko2]) = *reinterpret_cast<const uint4*>(Blo + gb2);
        __syncthreads();

        #pragma unroll
        for (int ks = 0; ks < 4; ks++) {
            const int kofs = ks * 16 + kg * 8;
            short8v ah = *reinterpret_cast<const short8v*>(&sAh[wr + l31][kofs]);
            short8v al = *reinterpret_cast<const short8v*>(&sAl[wr + l31][kofs]);
            short8v bh = *reinterpret_cast<const short8v*>(&sBh[wc + l31][kofs]);
            short8v bl = *reinterpret_cast<const short8v*>(&sBl[wc + l31][kofs]);
            acc = __builtin_amdgcn_mfma_f32_32x32x16_bf16(ah, bh, acc, 0, 0, 0);
            acc = __builtin_amdgcn_mfma_f32_32x32x16_bf16(ah, bl, acc, 0, 0, 0);
            acc = __builtin_amdgcn_mfma_f32_32x32x16_bf16(al, bh, acc, 0, 0, 0);
        }
        __syncthreads();
    }

    // epilogue: C/D layout (m74/m101): col = lane&31, row = (r&3) + 8*(r>>2) + 4*(lane>>5)
    const int colg = col0 + wc + l31;
    #pragma unroll
    for (int r = 0; r < 16; r++) {
        int rowg = row0 + wr + (r & 3) + 8 * (r >> 2) + 4 * kg;
        if (rowg < n) C[(size_t)rowg * Dout + colg] = acc[r];
    }
}

// ---------------- fused CSR aggregation + norm + bias + relu -> hi/lo bf16 ----------------
// post = ns (fold next layer's row-scale) or nullptr for the last layer.

template<int D>
__global__ __launch_bounds__(256) void agg_kernel(
        const float* __restrict__ h, const int* __restrict__ rowptr,
        const int* __restrict__ permSrc, const float* __restrict__ nd,
        const float* __restrict__ bias, const float* __restrict__ post,
        ushort* __restrict__ outH, ushort* __restrict__ outL, int n) {
    int node = blockIdx.x * 4 + (threadIdx.x >> 6);
    if (node >= n) return;
    int lane = threadIdx.x & 63;
    constexpr int V = D / 64;  // 2 or 4
    float acc[V];
    #pragma unroll
    for (int j = 0; j < V; j++) acc[j] = 0.0f;
    const int f0 = lane * V;
    int r0 = rowptr[node], r1 = rowptr[node + 1];
    for (int e = r0; e < r1; e++) {
        int sidx = permSrc[e];
        const float* hp = h + (size_t)sidx * D + f0;
        if constexpr (V == 4) {
            float4 v = *reinterpret_cast<const float4*>(hp);
            acc[0] += v.x; acc[1] += v.y; acc[2] += v.z; acc[3] += v.w;
        } else {
            float2 v = *reinterpret_cast<const float2*>(hp);
            acc[0] += v.x; acc[1] += v.y;
        }
    }
    float sc = nd[node];
    float ps = post ? post[node] : 1.0f;
    float r[V];
    #pragma unroll
    for (int j = 0; j < V; j++)
        r[j] = fmaxf(acc[j] * sc + bias[f0 + j], 0.0f) * ps;
    if constexpr (V == 4) {
        ushort4 hh, ll;
        split2(r[0], hh.x, ll.x);
        split2(r[1], hh.y, ll.y);
        split2(r[2], hh.z, ll.z);
        split2(r[3], hh.w, ll.w);
        *reinterpret_cast<ushort4*>(outH + (size_t)node * D + f0) = hh;
        *reinterpret_cast<ushort4*>(outL + (size_t)node * D + f0) = ll;
    } else {
        ushort2 hh, ll;
        split2(r[0], hh.x, ll.x);
        split2(r[1], hh.y, ll.y);
        *reinterpret_cast<ushort2*>(outH + (size_t)node * D + f0) = hh;
        *reinterpret_cast<ushort2*>(outL + (size_t)node * D + f0) = ll;
    }
}

// ---------------- classifier: out = h @ Wc + bc  (h reconstructed from hi/lo) ----------------

__global__ __launch_bounds__(256) void classifier_kernel(
        const ushort* __restrict__ hH, const ushort* __restrict__ hL,
        const float* __restrict__ Wc, const float* __restrict__ bc,
        float* __restrict__ out, int n) {
    __shared__ float Ws[256 * 4];
    int tid = threadIdx.x;
    for (int i = tid; i < 1024; i += 256) Ws[i] = Wc[i];
    __syncthreads();
    int node = blockIdx.x * 64 + (tid >> 2);
    int c = tid & 3;
    if (node < n) {
        float sum = bc[c];
        const ushort* hh = hH + (size_t)node * 256;
        const ushort* hl = hL + (size_t)node * 256;
        #pragma unroll 8
        for (int k = 0; k < 256; k++)
            sum = fmaf(bf2f(hh[k]) + bf2f(hl[k]), Ws[k * 4 + c], sum);
        out[(size_t)node * 4 + c] = sum;
    }
}

// ---------------- launch ----------------

extern "C" void kernel_launch(void* const* d_in, const int* in_sizes, int n_in,
                              void* d_out, int out_size, void* d_ws, size_t ws_size,
                              hipStream_t stream) {
    const float* x   = (const float*)d_in[0];
    const int*   src = (const int*)d_in[1];
    const int*   dst = (const int*)d_in[2];
    const float* W[4] = {(const float*)d_in[3], (const float*)d_in[5],
                         (const float*)d_in[7], (const float*)d_in[9]};
    const float* b[4] = {(const float*)d_in[4], (const float*)d_in[6],
                         (const float*)d_in[8], (const float*)d_in[10]};
    const float* Wc = (const float*)d_in[11];
    const float* bc = (const float*)d_in[12];
    float* out = (float*)d_out;

    // workspace layout (all 16B-aligned by construction)
    float*  G   = (float*)d_ws;                          // N*256 f32  (GEMM out)
    ushort* Ah  = (ushort*)(G + (size_t)NN * 256);       // N*256 ushort (act hi)
    ushort* Al  = Ah + (size_t)NN * 256;                 // N*256 ushort (act lo)
    float*  ns  = (float*)(Al + (size_t)NN * 256);       // N f32
    float*  nd  = ns + NN;                               // N f32
    ushort* Wth = (ushort*)(nd + NN);                    // 256*256 ushort (W^T hi)
    ushort* Wtl = Wth + 256 * 256;                       // 256*256 ushort (W^T lo)
    int*    rowptr  = (int*)(Wtl + 256 * 256);           // N+1 int
    int*    permSrc = rowptr + (NN + 1);                 // E int
    // transient scratch aliased into G (consumed before first GEMM writes G)
    int* degO   = (int*)G;
    int* degI   = degO + NN;
    int* cursor = degI + NN;
    int* bsum   = cursor + NN;
    (void)in_sizes; (void)n_in; (void)out_size; (void)ws_size;

    const int NB = (NN + SCAN_CHUNK - 1) / SCAN_CHUNK;

    // degrees + norms
    hipMemsetAsync(degO, 0, 2 * (size_t)NN * sizeof(int), stream);
    deg_kernel<<<(NEDGE + 255) / 256, 256, 0, stream>>>(src, dst, degO, degI, NEDGE);
    norm_kernel<<<(NN + 255) / 256, 256, 0, stream>>>(degO, degI, ns, nd, NN);

    // CSR build
    scan_reduce<<<NB, 256, 0, stream>>>(degI, bsum, NN);
    scan_bsums<<<1, 64, 0, stream>>>(bsum, NB);
    scan_final<<<NB, 256, 0, stream>>>(degI, bsum, rowptr, NN, NEDGE);
    copy_int<<<(NN + 255) / 256, 256, 0, stream>>>(rowptr, cursor, NN);
    scatter_kernel<<<(NEDGE + 255) / 256, 256, 0, stream>>>(src, dst, cursor, permSrc, NEDGE);

    // layer-0 input: hi/lo of x * ns
    convx_kernel<<<(NN * 32 + 255) / 256, 256, 0, stream>>>(x, ns, Ah, Al, NN);

    const int dims[5] = {128, 128, 128, 256, 256};

    for (int l = 0; l < 4; l++) {
        int K = dims[l], Dout = dims[l + 1];
        int logD = (Dout == 128) ? 7 : 8;

        // W^T hi/lo for this layer (tiny; reused buffer, stream-ordered)
        convw_kernel<<<((K << logD) + 255) / 256, 256, 0, stream>>>(W[l], Wth, Wtl, K, logD);

        dim3 ggrid((NN + 63) / 64, Dout / 64);
        gemm_mfma<<<ggrid, 256, 0, stream>>>(Ah, Al, Wth, Wtl, G, NN, K, Dout);

        int ablocks = (NN + 3) / 4;
        const float* post = (l < 3) ? ns : nullptr;  // fold next layer's row-scale; last layer unscaled
        if (Dout == 128)
            agg_kernel<128><<<ablocks, 256, 0, stream>>>(G, rowptr, permSrc, nd, b[l], post, Ah, Al, NN);
        else
            agg_kernel<256><<<ablocks, 256, 0, stream>>>(G, rowptr, permSrc, nd, b[l], post, Ah, Al, NN);
    }

    classifier_kernel<<<(NN + 63) / 64, 256, 0, stream>>>(Ah, Al, Wc, bc, out, NN);
}

// Round 5
// 756.819 us; speedup vs baseline: 3.6285x; 1.0892x over previous
//
#include <hip/hip_runtime.h>
#include <cstdint>
#include <cstddef>

#define NN 100000
#define NEDGE 800000
#define SCAN_CHUNK 2048

typedef __attribute__((ext_vector_type(8))) short short8v;
typedef __attribute__((ext_vector_type(16))) float float16v;

__device__ inline ushort f2bf(float f) {
    uint32_t u = __float_as_uint(f);
    u += 0x7fff + ((u >> 16) & 1);   // round-to-nearest-even
    return (ushort)(u >> 16);
}
__device__ inline float bf2f(ushort h) { return __uint_as_float(((uint32_t)h) << 16); }
__device__ inline void split2(float a, ushort& h, ushort& l) {
    h = f2bf(a);
    l = f2bf(a - bf2f(h));
}

// ---------------- degree + norm ----------------

__global__ void deg_kernel(const int* __restrict__ src, const int* __restrict__ dst,
                           int* __restrict__ dOut, int* __restrict__ dIn, int E) {
    int i = blockIdx.x * blockDim.x + threadIdx.x;
    if (i < E) {
        atomicAdd(&dOut[src[i]], 1);
        atomicAdd(&dIn[dst[i]], 1);
    }
}

__global__ void norm_kernel(const int* __restrict__ dOut, const int* __restrict__ dIn,
                            float* __restrict__ ns, float* __restrict__ nd, int n) {
    int i = blockIdx.x * blockDim.x + threadIdx.x;
    if (i < n) {
        int a = dOut[i] > 1 ? dOut[i] : 1;
        int b = dIn[i] > 1 ? dIn[i] : 1;
        ns[i] = 1.0f / sqrtf((float)a);
        nd[i] = 1.0f / sqrtf((float)b);
    }
}

// ---------------- exclusive scan of in-degrees -> rowptr ----------------

__global__ void scan_reduce(const int* __restrict__ deg, int* __restrict__ bsum, int n) {
    __shared__ int sdata[256];
    int b = blockIdx.x, t = threadIdx.x;
    int base = b * SCAN_CHUNK;
    int sum = 0;
    for (int i = t; i < SCAN_CHUNK; i += 256) {
        int idx = base + i;
        if (idx < n) sum += deg[idx];
    }
    sdata[t] = sum;
    __syncthreads();
    for (int s = 128; s > 0; s >>= 1) {
        if (t < s) sdata[t] += sdata[t + s];
        __syncthreads();
    }
    if (t == 0) bsum[b] = sdata[0];
}

__global__ void scan_bsums(int* bsum, int nb) {
    if (threadIdx.x == 0 && blockIdx.x == 0) {
        int acc = 0;
        for (int i = 0; i < nb; i++) { int v = bsum[i]; bsum[i] = acc; acc += v; }
    }
}

__global__ void scan_final(const int* __restrict__ deg, const int* __restrict__ bsum,
                           int* __restrict__ rowptr, int n, int E) {
    __shared__ int tsum[256];
    int b = blockIdx.x, t = threadIdx.x;
    int base = b * SCAN_CHUNK;
    int loc[8];
    int s = 0;
    #pragma unroll
    for (int i = 0; i < 8; i++) {
        int idx = base + t * 8 + i;
        loc[i] = s;
        s += (idx < n) ? deg[idx] : 0;
    }
    tsum[t] = s;
    __syncthreads();
    for (int off = 1; off < 256; off <<= 1) {
        int v = (t >= off) ? tsum[t - off] : 0;
        __syncthreads();
        tsum[t] += v;
        __syncthreads();
    }
    int prefix = bsum[b] + (t > 0 ? tsum[t - 1] : 0);
    #pragma unroll
    for (int i = 0; i < 8; i++) {
        int idx = base + t * 8 + i;
        if (idx < n) rowptr[idx] = prefix + loc[i];
    }
    if (b == 0 && t == 0) rowptr[n] = E;
}

__global__ void copy_int(const int* __restrict__ a, int* __restrict__ b, int n) {
    int i = blockIdx.x * blockDim.x + threadIdx.x;
    if (i < n) b[i] = a[i];
}

__global__ void scatter_kernel(const int* __restrict__ src, const int* __restrict__ dst,
                               int* __restrict__ cursor, int* __restrict__ permSrc, int E) {
    int i = blockIdx.x * blockDim.x + threadIdx.x;
    if (i < E) {
        int p = atomicAdd(&cursor[dst[i]], 1);
        permSrc[p] = src[i];
    }
}

// ---------------- converters ----------------
// x[N][128] * ns -> plain bf16 (gather payload for layer 0)
__global__ void convx_kernel(const float* __restrict__ x, const float* __restrict__ ns,
                             ushort* __restrict__ actB, int n) {
    int idx = blockIdx.x * blockDim.x + threadIdx.x;   // float4 units
    if (idx >= n * 32) return;
    int node = idx >> 5;
    int f0 = (idx & 31) * 4;
    float sc = ns[node];
    float4 v = *reinterpret_cast<const float4*>(x + (size_t)node * 128 + f0);
    ushort4 h;
    h.x = f2bf(v.x * sc);
    h.y = f2bf(v.y * sc);
    h.z = f2bf(v.z * sc);
    h.w = f2bf(v.w * sc);
    *reinterpret_cast<ushort4*>(actB + (size_t)node * 128 + f0) = h;
}

// W[K][Dout] -> transposed hi/lo [Dout][K]
__global__ void convw_kernel(const float* __restrict__ W, ushort* __restrict__ Bh,
                             ushort* __restrict__ Bl, int K, int logD) {
    int idx = blockIdx.x * blockDim.x + threadIdx.x;
    if (idx >= (K << logD)) return;
    int k = idx >> logD;
    int d = idx & ((1 << logD) - 1);
    ushort h, l;
    split2(W[idx], h, l);
    Bh[(size_t)d * K + k] = h;
    Bl[(size_t)d * K + k] = l;
}

// ---------------- CSR aggregation (bf16 gather) -> nd-scaled hi/lo split ----------------
// R[node] = nd[node] * sum_{e in CSR(node)} act[src[e]]   (act already ns-scaled)

template<int D>
__global__ __launch_bounds__(256) void agg_kernel(
        const ushort* __restrict__ act, const int* __restrict__ rowptr,
        const int* __restrict__ permSrc, const float* __restrict__ nd,
        ushort* __restrict__ outH, ushort* __restrict__ outL, int n) {
    int node = blockIdx.x * 4 + (threadIdx.x >> 6);
    if (node >= n) return;
    int lane = threadIdx.x & 63;
    constexpr int V = D / 64;  // 2 or 4
    float acc[V];
    #pragma unroll
    for (int j = 0; j < V; j++) acc[j] = 0.0f;
    const int f0 = lane * V;
    int r0 = rowptr[node], r1 = rowptr[node + 1];
    for (int e = r0; e < r1; e++) {
        int sidx = permSrc[e];
        const ushort* p = act + (size_t)sidx * D + f0;
        if constexpr (V == 4) {
            ushort4 v = *reinterpret_cast<const ushort4*>(p);
            acc[0] += bf2f(v.x); acc[1] += bf2f(v.y);
            acc[2] += bf2f(v.z); acc[3] += bf2f(v.w);
        } else {
            ushort2 v = *reinterpret_cast<const ushort2*>(p);
            acc[0] += bf2f(v.x); acc[1] += bf2f(v.y);
        }
    }
    float sc = nd[node];
    if constexpr (V == 4) {
        ushort4 hh, ll;
        split2(acc[0] * sc, hh.x, ll.x);
        split2(acc[1] * sc, hh.y, ll.y);
        split2(acc[2] * sc, hh.z, ll.z);
        split2(acc[3] * sc, hh.w, ll.w);
        *reinterpret_cast<ushort4*>(outH + (size_t)node * D + f0) = hh;
        *reinterpret_cast<ushort4*>(outL + (size_t)node * D + f0) = ll;
    } else {
        ushort2 hh, ll;
        split2(acc[0] * sc, hh.x, ll.x);
        split2(acc[1] * sc, hh.y, ll.y);
        *reinterpret_cast<ushort2*>(outH + (size_t)node * D + f0) = hh;
        *reinterpret_cast<ushort2*>(outL + (size_t)node * D + f0) = ll;
    }
}

// ---------------- MFMA GEMM with fused epilogue ----------------
// Cb[n][Dout] = bf16( relu( (Ahi+Alo)@(Bhi+Blo)^T + bias ) * (post ? post[row] : 1) )
// 64x64 tile, 4 waves in 2x2 quadrants of mfma_f32_32x32x16_bf16, K-step 64.

__global__ __launch_bounds__(256) void gemm_mfma(
        const ushort* __restrict__ Ahi, const ushort* __restrict__ Alo,
        const ushort* __restrict__ Bhi, const ushort* __restrict__ Blo,
        const float* __restrict__ bias, const float* __restrict__ post,
        ushort* __restrict__ Cb, int n, int K, int Dout) {
    __shared__ __align__(16) ushort sAh[64][72];
    __shared__ __align__(16) ushort sAl[64][72];
    __shared__ __align__(16) ushort sBh[64][72];
    __shared__ __align__(16) ushort sBl[64][72];
    const int tid = threadIdx.x;
    const int row0 = blockIdx.x * 64;
    const int col0 = blockIdx.y * 64;
    const int lane = tid & 63;
    const int wid = tid >> 6;
    const int wr = (wid >> 1) * 32;   // wave's row quadrant
    const int wc = (wid & 1) * 32;    // wave's col quadrant
    const int l31 = lane & 31;
    const int kg = lane >> 5;         // k-group (0/1)

    // staging map: 512 16B-chunks per buffer, 2 per thread
    const int c1 = tid, c2 = tid + 256;
    const int r1 = c1 >> 3, ko1 = (c1 & 7) * 8;
    const int r2 = c2 >> 3, ko2 = (c2 & 7) * 8;
    const uint4 zero4 = make_uint4(0u, 0u, 0u, 0u);

    float16v acc = {0.f,0.f,0.f,0.f,0.f,0.f,0.f,0.f,0.f,0.f,0.f,0.f,0.f,0.f,0.f,0.f};

    for (int k0 = 0; k0 < K; k0 += 64) {
        bool v1 = (row0 + r1) < n, v2 = (row0 + r2) < n;
        size_t ga1 = (size_t)(row0 + r1) * K + k0 + ko1;
        size_t ga2 = (size_t)(row0 + r2) * K + k0 + ko2;
        *reinterpret_cast<uint4*>(&sAh[r1][ko1]) = v1 ? *reinterpret_cast<const uint4*>(Ahi + ga1) : zero4;
        *reinterpret_cast<uint4*>(&sAh[r2][ko2]) = v2 ? *reinterpret_cast<const uint4*>(Ahi + ga2) : zero4;
        *reinterpret_cast<uint4*>(&sAl[r1][ko1]) = v1 ? *reinterpret_cast<const uint4*>(Alo + ga1) : zero4;
        *reinterpret_cast<uint4*>(&sAl[r2][ko2]) = v2 ? *reinterpret_cast<const uint4*>(Alo + ga2) : zero4;
        size_t gb1 = (size_t)(col0 + r1) * K + k0 + ko1;
        size_t gb2 = (size_t)(col0 + r2) * K + k0 + ko2;
        *reinterpret_cast<uint4*>(&sBh[r1][ko1]) = *reinterpret_cast<const uint4*>(Bhi + gb1);
        *reinterpret_cast<uint4*>(&sBh[r2][ko2]) = *reinterpret_cast<const uint4*>(Bhi + gb2);
        *reinterpret_cast<uint4*>(&sBl[r1][ko1]) = *reinterpret_cast<const uint4*>(Blo + gb1);
        *reinterpret_cast<uint4*>(&sBl[r2][ko2]) = *reinterpret_cast<const uint4*>(Blo + gb2);
        __syncthreads();

        #pragma unroll
        for (int ks = 0; ks < 4; ks++) {
            const int kofs = ks * 16 + kg * 8;
            short8v ah = *reinterpret_cast<const short8v*>(&sAh[wr + l31][kofs]);
            short8v al = *reinterpret_cast<const short8v*>(&sAl[wr + l31][kofs]);
            short8v bh = *reinterpret_cast<const short8v*>(&sBh[wc + l31][kofs]);
            short8v bl = *reinterpret_cast<const short8v*>(&sBl[wc + l31][kofs]);
            acc = __builtin_amdgcn_mfma_f32_32x32x16_bf16(ah, bh, acc, 0, 0, 0);
            acc = __builtin_amdgcn_mfma_f32_32x32x16_bf16(ah, bl, acc, 0, 0, 0);
            acc = __builtin_amdgcn_mfma_f32_32x32x16_bf16(al, bh, acc, 0, 0, 0);
        }
        __syncthreads();
    }

    // epilogue: C/D layout: col = lane&31, row = (r&3) + 8*(r>>2) + 4*(lane>>5)
    const int colg = col0 + wc + l31;
    const float bcol = bias[colg];
    #pragma unroll
    for (int r = 0; r < 16; r++) {
        int rowg = row0 + wr + (r & 3) + 8 * (r >> 2) + 4 * kg;
        if (rowg < n) {
            float v = fmaxf(acc[r] + bcol, 0.0f);
            if (post) v *= post[rowg];
            Cb[(size_t)rowg * Dout + colg] = f2bf(v);
        }
    }
}

// ---------------- classifier: out = h @ Wc + bc  (h is bf16, K=256, Dout=4) ----------------

__global__ __launch_bounds__(256) void classifier_kernel(
        const ushort* __restrict__ h, const float* __restrict__ Wc,
        const float* __restrict__ bc, float* __restrict__ out, int n) {
    __shared__ float Ws[256 * 4];
    int tid = threadIdx.x;
    for (int i = tid; i < 1024; i += 256) Ws[i] = Wc[i];
    __syncthreads();
    int node = blockIdx.x * 64 + (tid >> 2);
    int c = tid & 3;
    if (node < n) {
        float sum = bc[c];
        const ushort* hr = h + (size_t)node * 256;
        #pragma unroll
        for (int k0 = 0; k0 < 256; k0 += 8) {
            uint4 pk = *reinterpret_cast<const uint4*>(hr + k0);
            sum = fmaf(bf2f((ushort)(pk.x & 0xffff)), Ws[(k0 + 0) * 4 + c], sum);
            sum = fmaf(bf2f((ushort)(pk.x >> 16)),    Ws[(k0 + 1) * 4 + c], sum);
            sum = fmaf(bf2f((ushort)(pk.y & 0xffff)), Ws[(k0 + 2) * 4 + c], sum);
            sum = fmaf(bf2f((ushort)(pk.y >> 16)),    Ws[(k0 + 3) * 4 + c], sum);
            sum = fmaf(bf2f((ushort)(pk.z & 0xffff)), Ws[(k0 + 4) * 4 + c], sum);
            sum = fmaf(bf2f((ushort)(pk.z >> 16)),    Ws[(k0 + 5) * 4 + c], sum);
            sum = fmaf(bf2f((ushort)(pk.w & 0xffff)), Ws[(k0 + 6) * 4 + c], sum);
            sum = fmaf(bf2f((ushort)(pk.w >> 16)),    Ws[(k0 + 7) * 4 + c], sum);
        }
        out[(size_t)node * 4 + c] = sum;
    }
}

// ---------------- launch ----------------

extern "C" void kernel_launch(void* const* d_in, const int* in_sizes, int n_in,
                              void* d_out, int out_size, void* d_ws, size_t ws_size,
                              hipStream_t stream) {
    const float* x   = (const float*)d_in[0];
    const int*   src = (const int*)d_in[1];
    const int*   dst = (const int*)d_in[2];
    const float* W[4] = {(const float*)d_in[3], (const float*)d_in[5],
                         (const float*)d_in[7], (const float*)d_in[9]};
    const float* b[4] = {(const float*)d_in[4], (const float*)d_in[6],
                         (const float*)d_in[8], (const float*)d_in[10]};
    const float* Wc = (const float*)d_in[11];
    const float* bc = (const float*)d_in[12];
    float* out = (float*)d_out;

    // workspace layout (16B-aligned by construction)
    ushort* actB = (ushort*)d_ws;                        // N*256 ushort (bf16 activations, ns-scaled)
    ushort* Ah   = actB + (size_t)NN * 256;              // N*256 ushort (agg hi)
    ushort* Al   = Ah + (size_t)NN * 256;                // N*256 ushort (agg lo)
    float*  ns   = (float*)(Al + (size_t)NN * 256);      // N f32
    float*  nd   = ns + NN;                              // N f32
    ushort* Wth  = (ushort*)(nd + NN);                   // 256*256 ushort (W^T hi)
    ushort* Wtl  = Wth + 256 * 256;                      // 256*256 ushort (W^T lo)
    int*    rowptr  = (int*)(Wtl + 256 * 256);           // N+1 int
    int*    permSrc = rowptr + (NN + 1);                 // E int
    // transient scratch aliased into Ah (consumed before agg L0 writes Ah)
    int* degO   = (int*)Ah;
    int* degI   = degO + NN;
    int* cursor = degI + NN;
    int* bsum   = cursor + NN;
    (void)in_sizes; (void)n_in; (void)out_size; (void)ws_size;

    const int NB = (NN + SCAN_CHUNK - 1) / SCAN_CHUNK;

    // degrees + norms
    hipMemsetAsync(degO, 0, 2 * (size_t)NN * sizeof(int), stream);
    deg_kernel<<<(NEDGE + 255) / 256, 256, 0, stream>>>(src, dst, degO, degI, NEDGE);
    norm_kernel<<<(NN + 255) / 256, 256, 0, stream>>>(degO, degI, ns, nd, NN);

    // CSR build
    scan_reduce<<<NB, 256, 0, stream>>>(degI, bsum, NN);
    scan_bsums<<<1, 64, 0, stream>>>(bsum, NB);
    scan_final<<<NB, 256, 0, stream>>>(degI, bsum, rowptr, NN, NEDGE);
    copy_int<<<(NN + 255) / 256, 256, 0, stream>>>(rowptr, cursor, NN);
    scatter_kernel<<<(NEDGE + 255) / 256, 256, 0, stream>>>(src, dst, cursor, permSrc, NEDGE);

    // layer-0 gather payload: bf16(x * ns)
    convx_kernel<<<(NN * 32 + 255) / 256, 256, 0, stream>>>(x, ns, actB, NN);

    const int dims[5] = {128, 128, 128, 256, 256};

    for (int l = 0; l < 4; l++) {
        int K = dims[l], Dout = dims[l + 1];   // agg runs at width K (input side)
        int logD = (Dout == 128) ? 7 : 8;

        convw_kernel<<<((K << logD) + 255) / 256, 256, 0, stream>>>(W[l], Wth, Wtl, K, logD);

        // R = nd * agg(actB); hi/lo split for the GEMM
        int ablocks = (NN + 3) / 4;
        if (K == 128)
            agg_kernel<128><<<ablocks, 256, 0, stream>>>(actB, rowptr, permSrc, nd, Ah, Al, NN);
        else
            agg_kernel<256><<<ablocks, 256, 0, stream>>>(actB, rowptr, permSrc, nd, Ah, Al, NN);

        // actB' = bf16( relu(R@W + b) * (l<3 ? ns : 1) )
        const float* post = (l < 3) ? ns : nullptr;
        dim3 ggrid((NN + 63) / 64, Dout / 64);
        gemm_mfma<<<ggrid, 256, 0, stream>>>(Ah, Al, Wth, Wtl, b[l], post, actB, NN, K, Dout);
    }

    classifier_kernel<<<(NN + 63) / 64, 256, 0, stream>>>(actB, Wc, bc, out, NN);
}

// Round 6
// 695.971 us; speedup vs baseline: 3.9458x; 1.0874x over previous
//
#include <hip/hip_runtime.h>
#include <cstdint>
#include <cstddef>

#define NN 100000
#define NEDGE 800000
#define SCAN_CHUNK 2048

typedef __attribute__((ext_vector_type(8))) short short8v;
typedef __attribute__((ext_vector_type(16))) float float16v;

__device__ inline ushort f2bf(float f) {
    uint32_t u = __float_as_uint(f);
    u += 0x7fff + ((u >> 16) & 1);   // round-to-nearest-even
    return (ushort)(u >> 16);
}
__device__ inline float bf2f(ushort h) { return __uint_as_float(((uint32_t)h) << 16); }
__device__ inline void split2(float a, ushort& h, ushort& l) {
    h = f2bf(a);
    l = f2bf(a - bf2f(h));
}

// ---------------- degree + norm ----------------

__global__ void deg_kernel(const int* __restrict__ src, const int* __restrict__ dst,
                           int* __restrict__ dOut, int* __restrict__ dIn, int E) {
    int i = blockIdx.x * blockDim.x + threadIdx.x;
    if (i < E) {
        atomicAdd(&dOut[src[i]], 1);
        atomicAdd(&dIn[dst[i]], 1);
    }
}

__global__ void norm_kernel(const int* __restrict__ dOut, const int* __restrict__ dIn,
                            float* __restrict__ ns, float* __restrict__ nd, int n) {
    int i = blockIdx.x * blockDim.x + threadIdx.x;
    if (i < n) {
        int a = dOut[i] > 1 ? dOut[i] : 1;
        int b = dIn[i] > 1 ? dIn[i] : 1;
        ns[i] = 1.0f / sqrtf((float)a);
        nd[i] = 1.0f / sqrtf((float)b);
    }
}

// ---------------- exclusive scan of in-degrees -> rowptr ----------------

__global__ void scan_reduce(const int* __restrict__ deg, int* __restrict__ bsum, int n) {
    __shared__ int sdata[256];
    int b = blockIdx.x, t = threadIdx.x;
    int base = b * SCAN_CHUNK;
    int sum = 0;
    for (int i = t; i < SCAN_CHUNK; i += 256) {
        int idx = base + i;
        if (idx < n) sum += deg[idx];
    }
    sdata[t] = sum;
    __syncthreads();
    for (int s = 128; s > 0; s >>= 1) {
        if (t < s) sdata[t] += sdata[t + s];
        __syncthreads();
    }
    if (t == 0) bsum[b] = sdata[0];
}

__global__ void scan_bsums(int* bsum, int nb) {
    if (threadIdx.x == 0 && blockIdx.x == 0) {
        int acc = 0;
        for (int i = 0; i < nb; i++) { int v = bsum[i]; bsum[i] = acc; acc += v; }
    }
}

__global__ void scan_final(const int* __restrict__ deg, const int* __restrict__ bsum,
                           int* __restrict__ rowptr, int n, int E) {
    __shared__ int tsum[256];
    int b = blockIdx.x, t = threadIdx.x;
    int base = b * SCAN_CHUNK;
    int loc[8];
    int s = 0;
    #pragma unroll
    for (int i = 0; i < 8; i++) {
        int idx = base + t * 8 + i;
        loc[i] = s;
        s += (idx < n) ? deg[idx] : 0;
    }
    tsum[t] = s;
    __syncthreads();
    for (int off = 1; off < 256; off <<= 1) {
        int v = (t >= off) ? tsum[t - off] : 0;
        __syncthreads();
        tsum[t] += v;
        __syncthreads();
    }
    int prefix = bsum[b] + (t > 0 ? tsum[t - 1] : 0);
    #pragma unroll
    for (int i = 0; i < 8; i++) {
        int idx = base + t * 8 + i;
        if (idx < n) rowptr[idx] = prefix + loc[i];
    }
    if (b == 0 && t == 0) rowptr[n] = E;
}

__global__ void copy_int(const int* __restrict__ a, int* __restrict__ b, int n) {
    int i = blockIdx.x * blockDim.x + threadIdx.x;
    if (i < n) b[i] = a[i];
}

__global__ void scatter_kernel(const int* __restrict__ src, const int* __restrict__ dst,
                               int* __restrict__ cursor, int* __restrict__ permSrc, int E) {
    int i = blockIdx.x * blockDim.x + threadIdx.x;
    if (i < E) {
        int p = atomicAdd(&cursor[dst[i]], 1);
        permSrc[p] = src[i];
    }
}

// ---------------- converters ----------------
__global__ void convx_kernel(const float* __restrict__ x, const float* __restrict__ ns,
                             ushort* __restrict__ actB, int n) {
    int idx = blockIdx.x * blockDim.x + threadIdx.x;   // float4 units
    if (idx >= n * 32) return;
    int node = idx >> 5;
    int f0 = (idx & 31) * 4;
    float sc = ns[node];
    float4 v = *reinterpret_cast<const float4*>(x + (size_t)node * 128 + f0);
    ushort4 h;
    h.x = f2bf(v.x * sc);
    h.y = f2bf(v.y * sc);
    h.z = f2bf(v.z * sc);
    h.w = f2bf(v.w * sc);
    *reinterpret_cast<ushort4*>(actB + (size_t)node * 128 + f0) = h;
}

__global__ void convw_kernel(const float* __restrict__ W, ushort* __restrict__ Bh,
                             ushort* __restrict__ Bl, int K, int logD) {
    int idx = blockIdx.x * blockDim.x + threadIdx.x;
    if (idx >= (K << logD)) return;
    int k = idx >> logD;
    int d = idx & ((1 << logD) - 1);
    ushort h, l;
    split2(W[idx], h, l);
    Bh[(size_t)d * K + k] = h;
    Bl[(size_t)d * K + k] = l;
}

// ---------------- CSR aggregation (bf16 gather, MLP-unrolled) ----------------
// R[node] = nd[node] * sum_{e in CSR(node)} act[src[e]]  -> hi/lo split

__device__ inline void acc4(float& a0, float& a1, float& a2, float& a3, ushort4 v) {
    a0 += bf2f(v.x); a1 += bf2f(v.y); a2 += bf2f(v.z); a3 += bf2f(v.w);
}

template<int D>
__global__ __launch_bounds__(256) void agg_kernel(
        const ushort* __restrict__ act, const int* __restrict__ rowptr,
        const int* __restrict__ permSrc, const float* __restrict__ nd,
        ushort* __restrict__ outH, ushort* __restrict__ outL, int n) {
    int node = blockIdx.x * 4 + (threadIdx.x >> 6);
    if (node >= n) return;
    int lane = threadIdx.x & 63;
    int r0 = rowptr[node], r1 = rowptr[node + 1];
    float sc = nd[node];
    float a0 = 0.f, a1 = 0.f, a2 = 0.f, a3 = 0.f;

    if constexpr (D == 256) {
        const int f0 = lane * 4;    // 64 lanes x 4 feats
        int e = r0;
        for (; e + 3 < r1; e += 4) {
            int s0 = permSrc[e], s1 = permSrc[e + 1], s2 = permSrc[e + 2], s3 = permSrc[e + 3];
            ushort4 v0 = *reinterpret_cast<const ushort4*>(act + (size_t)s0 * 256 + f0);
            ushort4 v1 = *reinterpret_cast<const ushort4*>(act + (size_t)s1 * 256 + f0);
            ushort4 v2 = *reinterpret_cast<const ushort4*>(act + (size_t)s2 * 256 + f0);
            ushort4 v3 = *reinterpret_cast<const ushort4*>(act + (size_t)s3 * 256 + f0);
            acc4(a0, a1, a2, a3, v0);
            acc4(a0, a1, a2, a3, v1);
            acc4(a0, a1, a2, a3, v2);
            acc4(a0, a1, a2, a3, v3);
        }
        for (; e < r1; e++) {
            int s = permSrc[e];
            acc4(a0, a1, a2, a3, *reinterpret_cast<const ushort4*>(act + (size_t)s * 256 + f0));
        }
        ushort4 hh, ll;
        split2(a0 * sc, hh.x, ll.x);
        split2(a1 * sc, hh.y, ll.y);
        split2(a2 * sc, hh.z, ll.z);
        split2(a3 * sc, hh.w, ll.w);
        *reinterpret_cast<ushort4*>(outH + (size_t)node * 256 + f0) = hh;
        *reinterpret_cast<ushort4*>(outL + (size_t)node * 256 + f0) = ll;
    } else {
        // D == 128: half-wave per edge; lanes 0-31 take even edges, 32-63 odd.
        const int half = lane >> 5;
        const int f0 = (lane & 31) * 4;  // 32 lanes x 4 feats
        int e = r0 + half;
        for (; e + 6 < r1; e += 8) {     // 4 strided loads per half = 8 edges/wave in flight
            int s0 = permSrc[e], s1 = permSrc[e + 2], s2 = permSrc[e + 4], s3 = permSrc[e + 6];
            ushort4 v0 = *reinterpret_cast<const ushort4*>(act + (size_t)s0 * 128 + f0);
            ushort4 v1 = *reinterpret_cast<const ushort4*>(act + (size_t)s1 * 128 + f0);
            ushort4 v2 = *reinterpret_cast<const ushort4*>(act + (size_t)s2 * 128 + f0);
            ushort4 v3 = *reinterpret_cast<const ushort4*>(act + (size_t)s3 * 128 + f0);
            acc4(a0, a1, a2, a3, v0);
            acc4(a0, a1, a2, a3, v1);
            acc4(a0, a1, a2, a3, v2);
            acc4(a0, a1, a2, a3, v3);
        }
        for (; e < r1; e += 2) {
            int s = permSrc[e];
            acc4(a0, a1, a2, a3, *reinterpret_cast<const ushort4*>(act + (size_t)s * 128 + f0));
        }
        // combine half-waves (lane i <-> lane i+32 hold the same features)
        a0 += __shfl_xor(a0, 32);
        a1 += __shfl_xor(a1, 32);
        a2 += __shfl_xor(a2, 32);
        a3 += __shfl_xor(a3, 32);
        if (half == 0) {
            ushort4 hh, ll;
            split2(a0 * sc, hh.x, ll.x);
            split2(a1 * sc, hh.y, ll.y);
            split2(a2 * sc, hh.z, ll.z);
            split2(a3 * sc, hh.w, ll.w);
            *reinterpret_cast<ushort4*>(outH + (size_t)node * 128 + f0) = hh;
            *reinterpret_cast<ushort4*>(outL + (size_t)node * 128 + f0) = ll;
        }
    }
}

// ---------------- MFMA GEMM with fused epilogue ----------------
// Cb[n][Dout] = bf16( relu( (Ahi+Alo)@(Bhi+Blo)^T + bias ) * (post ? post[row] : 1) )
// 128x64 tile, 4 waves; wave w owns rows [32w,32w+32), both 32-col blocks.

__global__ __launch_bounds__(256) void gemm_mfma(
        const ushort* __restrict__ Ahi, const ushort* __restrict__ Alo,
        const ushort* __restrict__ Bhi, const ushort* __restrict__ Blo,
        const float* __restrict__ bias, const float* __restrict__ post,
        ushort* __restrict__ Cb, int n, int K, int Dout) {
    __shared__ __align__(16) ushort sAh[128][72];
    __shared__ __align__(16) ushort sAl[128][72];
    __shared__ __align__(16) ushort sBh[64][72];
    __shared__ __align__(16) ushort sBl[64][72];
    const int tid = threadIdx.x;
    const int row0 = blockIdx.x * 128;
    const int col0 = blockIdx.y * 64;
    const int lane = tid & 63;
    const int wid = tid >> 6;
    const int l31 = lane & 31;
    const int kg = lane >> 5;         // k-group (0/1)
    const uint4 zero4 = make_uint4(0u, 0u, 0u, 0u);

    float16v acc0 = {0.f,0.f,0.f,0.f,0.f,0.f,0.f,0.f,0.f,0.f,0.f,0.f,0.f,0.f,0.f,0.f};
    float16v acc1 = {0.f,0.f,0.f,0.f,0.f,0.f,0.f,0.f,0.f,0.f,0.f,0.f,0.f,0.f,0.f,0.f};

    for (int k0 = 0; k0 < K; k0 += 64) {
        // stage A: 128x64 ushorts = 1024 16B-chunks -> 4 per thread (hi and lo)
        #pragma unroll
        for (int i = 0; i < 4; i++) {
            int c = tid + i * 256;
            int r = c >> 3, ko = (c & 7) * 8;
            bool v = (row0 + r) < n;
            size_t ga = (size_t)(row0 + r) * K + k0 + ko;
            *reinterpret_cast<uint4*>(&sAh[r][ko]) = v ? *reinterpret_cast<const uint4*>(Ahi + ga) : zero4;
            *reinterpret_cast<uint4*>(&sAl[r][ko]) = v ? *reinterpret_cast<const uint4*>(Alo + ga) : zero4;
        }
        // stage B: 64x64 ushorts = 512 chunks -> 2 per thread (hi and lo)
        #pragma unroll
        for (int i = 0; i < 2; i++) {
            int c = tid + i * 256;
            int r = c >> 3, ko = (c & 7) * 8;
            size_t gb = (size_t)(col0 + r) * K + k0 + ko;
            *reinterpret_cast<uint4*>(&sBh[r][ko]) = *reinterpret_cast<const uint4*>(Bhi + gb);
            *reinterpret_cast<uint4*>(&sBl[r][ko]) = *reinterpret_cast<const uint4*>(Blo + gb);
        }
        __syncthreads();

        #pragma unroll
        for (int ks = 0; ks < 4; ks++) {
            const int kofs = ks * 16 + kg * 8;
            short8v ah = *reinterpret_cast<const short8v*>(&sAh[wid * 32 + l31][kofs]);
            short8v al = *reinterpret_cast<const short8v*>(&sAl[wid * 32 + l31][kofs]);
            short8v bh0 = *reinterpret_cast<const short8v*>(&sBh[l31][kofs]);
            short8v bl0 = *reinterpret_cast<const short8v*>(&sBl[l31][kofs]);
            short8v bh1 = *reinterpret_cast<const short8v*>(&sBh[32 + l31][kofs]);
            short8v bl1 = *reinterpret_cast<const short8v*>(&sBl[32 + l31][kofs]);
            acc0 = __builtin_amdgcn_mfma_f32_32x32x16_bf16(ah, bh0, acc0, 0, 0, 0);
            acc1 = __builtin_amdgcn_mfma_f32_32x32x16_bf16(ah, bh1, acc1, 0, 0, 0);
            acc0 = __builtin_amdgcn_mfma_f32_32x32x16_bf16(ah, bl0, acc0, 0, 0, 0);
            acc1 = __builtin_amdgcn_mfma_f32_32x32x16_bf16(ah, bl1, acc1, 0, 0, 0);
            acc0 = __builtin_amdgcn_mfma_f32_32x32x16_bf16(al, bh0, acc0, 0, 0, 0);
            acc1 = __builtin_amdgcn_mfma_f32_32x32x16_bf16(al, bh1, acc1, 0, 0, 0);
        }
        __syncthreads();
    }

    // epilogue: C/D layout: col = lane&31, row = (r&3) + 8*(r>>2) + 4*(lane>>5)
    const int rbase = row0 + wid * 32;
    #pragma unroll
    for (int cb = 0; cb < 2; cb++) {
        const int colg = col0 + cb * 32 + l31;
        const float bcol = bias[colg];
        const float16v& acc = cb ? acc1 : acc0;
        #pragma unroll
        for (int r = 0; r < 16; r++) {
            int rowg = rbase + (r & 3) + 8 * (r >> 2) + 4 * kg;
            if (rowg < n) {
                float v = fmaxf(acc[r] + bcol, 0.0f);
                if (post) v *= post[rowg];
                Cb[(size_t)rowg * Dout + colg] = f2bf(v);
            }
        }
    }
}

// ---------------- classifier: out = h @ Wc + bc  (h is bf16, K=256, Dout=4) ----------------

__global__ __launch_bounds__(256) void classifier_kernel(
        const ushort* __restrict__ h, const float* __restrict__ Wc,
        const float* __restrict__ bc, float* __restrict__ out, int n) {
    __shared__ float Ws[256 * 4];
    int tid = threadIdx.x;
    for (int i = tid; i < 1024; i += 256) Ws[i] = Wc[i];
    __syncthreads();
    int node = blockIdx.x * 64 + (tid >> 2);
    int c = tid & 3;
    if (node < n) {
        float sum = bc[c];
        const ushort* hr = h + (size_t)node * 256;
        #pragma unroll
        for (int k0 = 0; k0 < 256; k0 += 8) {
            uint4 pk = *reinterpret_cast<const uint4*>(hr + k0);
            sum = fmaf(bf2f((ushort)(pk.x & 0xffff)), Ws[(k0 + 0) * 4 + c], sum);
            sum = fmaf(bf2f((ushort)(pk.x >> 16)),    Ws[(k0 + 1) * 4 + c], sum);
            sum = fmaf(bf2f((ushort)(pk.y & 0xffff)), Ws[(k0 + 2) * 4 + c], sum);
            sum = fmaf(bf2f((ushort)(pk.y >> 16)),    Ws[(k0 + 3) * 4 + c], sum);
            sum = fmaf(bf2f((ushort)(pk.z & 0xffff)), Ws[(k0 + 4) * 4 + c], sum);
            sum = fmaf(bf2f((ushort)(pk.z >> 16)),    Ws[(k0 + 5) * 4 + c], sum);
            sum = fmaf(bf2f((ushort)(pk.w & 0xffff)), Ws[(k0 + 6) * 4 + c], sum);
            sum = fmaf(bf2f((ushort)(pk.w >> 16)),    Ws[(k0 + 7) * 4 + c], sum);
        }
        out[(size_t)node * 4 + c] = sum;
    }
}

// ---------------- launch ----------------

extern "C" void kernel_launch(void* const* d_in, const int* in_sizes, int n_in,
                              void* d_out, int out_size, void* d_ws, size_t ws_size,
                              hipStream_t stream) {
    const float* x   = (const float*)d_in[0];
    const int*   src = (const int*)d_in[1];
    const int*   dst = (const int*)d_in[2];
    const float* W[4] = {(const float*)d_in[3], (const float*)d_in[5],
                         (const float*)d_in[7], (const float*)d_in[9]};
    const float* b[4] = {(const float*)d_in[4], (const float*)d_in[6],
                         (const float*)d_in[8], (const float*)d_in[10]};
    const float* Wc = (const float*)d_in[11];
    const float* bc = (const float*)d_in[12];
    float* out = (float*)d_out;

    // workspace layout (16B-aligned by construction)
    ushort* actB = (ushort*)d_ws;                        // N*256 ushort (bf16 activations, ns-scaled)
    ushort* Ah   = actB + (size_t)NN * 256;              // N*256 ushort (agg hi)
    ushort* Al   = Ah + (size_t)NN * 256;                // N*256 ushort (agg lo)
    float*  ns   = (float*)(Al + (size_t)NN * 256);      // N f32
    float*  nd   = ns + NN;                              // N f32
    ushort* Wth  = (ushort*)(nd + NN);                   // 256*256 ushort (W^T hi)
    ushort* Wtl  = Wth + 256 * 256;                      // 256*256 ushort (W^T lo)
    int*    rowptr  = (int*)(Wtl + 256 * 256);           // N+1 int
    int*    permSrc = rowptr + (NN + 1);                 // E int
    // transient scratch aliased into Ah (consumed before agg L0 writes Ah)
    int* degO   = (int*)Ah;
    int* degI   = degO + NN;
    int* cursor = degI + NN;
    int* bsum   = cursor + NN;
    (void)in_sizes; (void)n_in; (void)out_size; (void)ws_size;

    const int NB = (NN + SCAN_CHUNK - 1) / SCAN_CHUNK;

    // degrees + norms
    hipMemsetAsync(degO, 0, 2 * (size_t)NN * sizeof(int), stream);
    deg_kernel<<<(NEDGE + 255) / 256, 256, 0, stream>>>(src, dst, degO, degI, NEDGE);
    norm_kernel<<<(NN + 255) / 256, 256, 0, stream>>>(degO, degI, ns, nd, NN);

    // CSR build
    scan_reduce<<<NB, 256, 0, stream>>>(degI, bsum, NN);
    scan_bsums<<<1, 64, 0, stream>>>(bsum, NB);
    scan_final<<<NB, 256, 0, stream>>>(degI, bsum, rowptr, NN, NEDGE);
    copy_int<<<(NN + 255) / 256, 256, 0, stream>>>(rowptr, cursor, NN);
    scatter_kernel<<<(NEDGE + 255) / 256, 256, 0, stream>>>(src, dst, cursor, permSrc, NEDGE);

    // layer-0 gather payload: bf16(x * ns)
    convx_kernel<<<(NN * 32 + 255) / 256, 256, 0, stream>>>(x, ns, actB, NN);

    const int dims[5] = {128, 128, 128, 256, 256};

    for (int l = 0; l < 4; l++) {
        int K = dims[l], Dout = dims[l + 1];   // agg runs at width K (input side)
        int logD = (Dout == 128) ? 7 : 8;

        convw_kernel<<<((K << logD) + 255) / 256, 256, 0, stream>>>(W[l], Wth, Wtl, K, logD);

        // R = nd * agg(actB); hi/lo split for the GEMM
        int ablocks = (NN + 3) / 4;
        if (K == 128)
            agg_kernel<128><<<ablocks, 256, 0, stream>>>(actB, rowptr, permSrc, nd, Ah, Al, NN);
        else
            agg_kernel<256><<<ablocks, 256, 0, stream>>>(actB, rowptr, permSrc, nd, Ah, Al, NN);

        // actB' = bf16( relu(R@W + b) * (l<3 ? ns : 1) )
        const float* post = (l < 3) ? ns : nullptr;
        dim3 ggrid((NN + 127) / 128, Dout / 64);
        gemm_mfma<<<ggrid, 256, 0, stream>>>(Ah, Al, Wth, Wtl, b[l], post, actB, NN, K, Dout);
    }

    classifier_kernel<<<(NN + 63) / 64, 256, 0, stream>>>(actB, Wc, bc, out, NN);
}

// Round 7
// 663.292 us; speedup vs baseline: 4.1402x; 1.0493x over previous
//
#include <hip/hip_runtime.h>
#include <cstdint>
#include <cstddef>

#define NN 100000
#define NEDGE 800000
#define SCAN_CHUNK 2048

typedef __attribute__((ext_vector_type(8))) short short8v;
typedef __attribute__((ext_vector_type(16))) float float16v;

__device__ inline ushort f2bf(float f) {
    uint32_t u = __float_as_uint(f);
    u += 0x7fff + ((u >> 16) & 1);   // round-to-nearest-even
    return (ushort)(u >> 16);
}
__device__ inline float bf2f(ushort h) { return __uint_as_float(((uint32_t)h) << 16); }
__device__ inline void split2(float a, ushort& h, ushort& l) {
    h = f2bf(a);
    l = f2bf(a - bf2f(h));
}

// ---------------- degree + norm ----------------

__global__ void deg_kernel(const int* __restrict__ src, const int* __restrict__ dst,
                           int* __restrict__ dOut, int* __restrict__ dIn, int E) {
    int i = blockIdx.x * blockDim.x + threadIdx.x;
    if (i < E) {
        atomicAdd(&dOut[src[i]], 1);
        atomicAdd(&dIn[dst[i]], 1);
    }
}

__global__ void norm_kernel(const int* __restrict__ dOut, const int* __restrict__ dIn,
                            float* __restrict__ ns, float* __restrict__ nd, int n) {
    int i = blockIdx.x * blockDim.x + threadIdx.x;
    if (i < n) {
        int a = dOut[i] > 1 ? dOut[i] : 1;
        int b = dIn[i] > 1 ? dIn[i] : 1;
        ns[i] = 1.0f / sqrtf((float)a);
        nd[i] = 1.0f / sqrtf((float)b);
    }
}

// ---------------- exclusive scan of in-degrees -> rowptr ----------------

__global__ void scan_reduce(const int* __restrict__ deg, int* __restrict__ bsum, int n) {
    __shared__ int sdata[256];
    int b = blockIdx.x, t = threadIdx.x;
    int base = b * SCAN_CHUNK;
    int sum = 0;
    for (int i = t; i < SCAN_CHUNK; i += 256) {
        int idx = base + i;
        if (idx < n) sum += deg[idx];
    }
    sdata[t] = sum;
    __syncthreads();
    for (int s = 128; s > 0; s >>= 1) {
        if (t < s) sdata[t] += sdata[t + s];
        __syncthreads();
    }
    if (t == 0) bsum[b] = sdata[0];
}

__global__ void scan_bsums(int* bsum, int nb) {
    if (threadIdx.x == 0 && blockIdx.x == 0) {
        int acc = 0;
        for (int i = 0; i < nb; i++) { int v = bsum[i]; bsum[i] = acc; acc += v; }
    }
}

__global__ void scan_final(const int* __restrict__ deg, const int* __restrict__ bsum,
                           int* __restrict__ rowptr, int n, int E) {
    __shared__ int tsum[256];
    int b = blockIdx.x, t = threadIdx.x;
    int base = b * SCAN_CHUNK;
    int loc[8];
    int s = 0;
    #pragma unroll
    for (int i = 0; i < 8; i++) {
        int idx = base + t * 8 + i;
        loc[i] = s;
        s += (idx < n) ? deg[idx] : 0;
    }
    tsum[t] = s;
    __syncthreads();
    for (int off = 1; off < 256; off <<= 1) {
        int v = (t >= off) ? tsum[t - off] : 0;
        __syncthreads();
        tsum[t] += v;
        __syncthreads();
    }
    int prefix = bsum[b] + (t > 0 ? tsum[t - 1] : 0);
    #pragma unroll
    for (int i = 0; i < 8; i++) {
        int idx = base + t * 8 + i;
        if (idx < n) rowptr[idx] = prefix + loc[i];
    }
    if (b == 0 && t == 0) rowptr[n] = E;
}

__global__ void copy_int(const int* __restrict__ a, int* __restrict__ b, int n) {
    int i = blockIdx.x * blockDim.x + threadIdx.x;
    if (i < n) b[i] = a[i];
}

__global__ void scatter_kernel(const int* __restrict__ src, const int* __restrict__ dst,
                               int* __restrict__ cursor, int* __restrict__ permSrc, int E) {
    int i = blockIdx.x * blockDim.x + threadIdx.x;
    if (i < E) {
        int p = atomicAdd(&cursor[dst[i]], 1);
        permSrc[p] = src[i];
    }
}

// ---------------- converters ----------------
__global__ void convx_kernel(const float* __restrict__ x, const float* __restrict__ ns,
                             ushort* __restrict__ actB, int n) {
    int idx = blockIdx.x * blockDim.x + threadIdx.x;   // float4 units
    if (idx >= n * 32) return;
    int node = idx >> 5;
    int f0 = (idx & 31) * 4;
    float sc = ns[node];
    float4 v = *reinterpret_cast<const float4*>(x + (size_t)node * 128 + f0);
    ushort4 h;
    h.x = f2bf(v.x * sc);
    h.y = f2bf(v.y * sc);
    h.z = f2bf(v.z * sc);
    h.w = f2bf(v.w * sc);
    *reinterpret_cast<ushort4*>(actB + (size_t)node * 128 + f0) = h;
}

__global__ void convw_kernel(const float* __restrict__ W, ushort* __restrict__ Bh,
                             ushort* __restrict__ Bl, int K, int logD) {
    int idx = blockIdx.x * blockDim.x + threadIdx.x;
    if (idx >= (K << logD)) return;
    int k = idx >> logD;
    int d = idx & ((1 << logD) - 1);
    ushort h, l;
    split2(W[idx], h, l);
    Bh[(size_t)d * K + k] = h;
    Bl[(size_t)d * K + k] = l;
}

// ---------------- CSR aggregation: 16B gather loads, edge-group MLP ----------------
// R[node] = nd[node] * sum_{e in CSR(node)} act[src[e]]  -> hi/lo split

__device__ inline void accum8(float* a, uint4 v) {
    a[0] += __uint_as_float(v.x << 16);
    a[1] += __uint_as_float(v.x & 0xffff0000u);
    a[2] += __uint_as_float(v.y << 16);
    a[3] += __uint_as_float(v.y & 0xffff0000u);
    a[4] += __uint_as_float(v.z << 16);
    a[5] += __uint_as_float(v.z & 0xffff0000u);
    a[6] += __uint_as_float(v.w << 16);
    a[7] += __uint_as_float(v.w & 0xffff0000u);
}

template<int D>
__global__ __launch_bounds__(256) void agg_kernel(
        const ushort* __restrict__ act, const int* __restrict__ rowptr,
        const int* __restrict__ permSrc, const float* __restrict__ nd,
        ushort* __restrict__ outH, ushort* __restrict__ outL, int n) {
    int node = blockIdx.x * 4 + (threadIdx.x >> 6);
    if (node >= n) return;
    int lane = threadIdx.x & 63;
    constexpr int GROUPS = (D == 256) ? 2 : 4;   // edge slices per wave
    constexpr int GL = 64 / GROUPS;              // lanes per slice (32 / 16)
    const int g  = lane / GL;
    const int gl = lane % GL;
    const int f0 = gl * 8;                       // 8 bf16 per lane (16B)
    float a[8] = {0.f,0.f,0.f,0.f,0.f,0.f,0.f,0.f};
    int r0 = rowptr[node], r1 = rowptr[node + 1];

    int e = r0 + g;
    for (; e + 3 * GROUPS < r1; e += 4 * GROUPS) {
        int s0 = permSrc[e];
        int s1 = permSrc[e + GROUPS];
        int s2 = permSrc[e + 2 * GROUPS];
        int s3 = permSrc[e + 3 * GROUPS];
        uint4 v0 = *reinterpret_cast<const uint4*>(act + (size_t)s0 * D + f0);
        uint4 v1 = *reinterpret_cast<const uint4*>(act + (size_t)s1 * D + f0);
        uint4 v2 = *reinterpret_cast<const uint4*>(act + (size_t)s2 * D + f0);
        uint4 v3 = *reinterpret_cast<const uint4*>(act + (size_t)s3 * D + f0);
        accum8(a, v0); accum8(a, v1); accum8(a, v2); accum8(a, v3);
    }
    for (; e < r1; e += GROUPS) {
        int s = permSrc[e];
        accum8(a, *reinterpret_cast<const uint4*>(act + (size_t)s * D + f0));
    }

    #pragma unroll
    for (int j = 0; j < 8; j++) {
        if constexpr (GROUPS == 4) a[j] += __shfl_xor(a[j], 16);
        a[j] += __shfl_xor(a[j], 32);
    }

    if (g == 0) {
        float sc = nd[node];
        union { ushort u[8]; uint4 v; } H, L;
        #pragma unroll
        for (int j = 0; j < 8; j++) split2(a[j] * sc, H.u[j], L.u[j]);
        *reinterpret_cast<uint4*>(outH + (size_t)node * D + f0) = H.v;
        *reinterpret_cast<uint4*>(outL + (size_t)node * D + f0) = L.v;
    }
}

// ---------------- MFMA GEMM with fused epilogue ----------------
// Cb[n][Dout] = bf16( relu( (Ahi+Alo)@(Bhi+Blo)^T + bias ) * (post ? post[row] : 1) )
// 128x64 tile, 4 waves (wave = 32 rows x 64 cols). Grid: x = col-blocks (fast)
// so consecutive blocks share the A panel -> L2/L3 reuse.
// LDS: no padding; 16B-chunk XOR swizzle: LDS[r][chunk c] holds global chunk
// c ^ (r&7) (involution, applied on write-source and read).

__global__ __launch_bounds__(256) void gemm_mfma(
        const ushort* __restrict__ Ahi, const ushort* __restrict__ Alo,
        const ushort* __restrict__ Bhi, const ushort* __restrict__ Blo,
        const float* __restrict__ bias, const float* __restrict__ post,
        ushort* __restrict__ Cb, int n, int K, int Dout) {
    __shared__ __align__(16) ushort sAh[128][64];
    __shared__ __align__(16) ushort sAl[128][64];
    __shared__ __align__(16) ushort sBh[64][64];
    __shared__ __align__(16) ushort sBl[64][64];
    const int tid = threadIdx.x;
    const int col0 = blockIdx.x * 64;
    const int row0 = blockIdx.y * 128;
    const int lane = tid & 63;
    const int wid = tid >> 6;
    const int l31 = lane & 31;
    const int kg = lane >> 5;         // k-group (0/1)
    const uint4 zero4 = make_uint4(0u, 0u, 0u, 0u);

    float16v acc0 = {0.f,0.f,0.f,0.f,0.f,0.f,0.f,0.f,0.f,0.f,0.f,0.f,0.f,0.f,0.f,0.f};
    float16v acc1 = {0.f,0.f,0.f,0.f,0.f,0.f,0.f,0.f,0.f,0.f,0.f,0.f,0.f,0.f,0.f,0.f};

    for (int k0 = 0; k0 < K; k0 += 64) {
        // stage A: 128 rows x 8 chunks = 1024 chunks -> 4 per thread
        #pragma unroll
        for (int i = 0; i < 4; i++) {
            int c = tid + i * 256;
            int r = c >> 3, ch = c & 7;
            int gch = ch ^ (r & 7);              // global chunk this slot holds
            bool v = (row0 + r) < n;
            size_t ga = (size_t)(row0 + r) * K + k0 + gch * 8;
            *reinterpret_cast<uint4*>(&sAh[r][ch * 8]) = v ? *reinterpret_cast<const uint4*>(Ahi + ga) : zero4;
            *reinterpret_cast<uint4*>(&sAl[r][ch * 8]) = v ? *reinterpret_cast<const uint4*>(Alo + ga) : zero4;
        }
        // stage B: 64 rows x 8 chunks = 512 chunks -> 2 per thread
        #pragma unroll
        for (int i = 0; i < 2; i++) {
            int c = tid + i * 256;
            int r = c >> 3, ch = c & 7;
            int gch = ch ^ (r & 7);
            size_t gb = (size_t)(col0 + r) * K + k0 + gch * 8;
            *reinterpret_cast<uint4*>(&sBh[r][ch * 8]) = *reinterpret_cast<const uint4*>(Bhi + gb);
            *reinterpret_cast<uint4*>(&sBl[r][ch * 8]) = *reinterpret_cast<const uint4*>(Blo + gb);
        }
        __syncthreads();

        #pragma unroll
        for (int ks = 0; ks < 4; ks++) {
            const int gw = ks * 2 + kg;          // wanted global chunk
            const int rA = wid * 32 + l31;
            const int rB0 = l31, rB1 = 32 + l31;
            short8v ah = *reinterpret_cast<const short8v*>(&sAh[rA][(gw ^ (rA & 7)) * 8]);
            short8v al = *reinterpret_cast<const short8v*>(&sAl[rA][(gw ^ (rA & 7)) * 8]);
            short8v bh0 = *reinterpret_cast<const short8v*>(&sBh[rB0][(gw ^ (rB0 & 7)) * 8]);
            short8v bl0 = *reinterpret_cast<const short8v*>(&sBl[rB0][(gw ^ (rB0 & 7)) * 8]);
            short8v bh1 = *reinterpret_cast<const short8v*>(&sBh[rB1][(gw ^ (rB1 & 7)) * 8]);
            short8v bl1 = *reinterpret_cast<const short8v*>(&sBl[rB1][(gw ^ (rB1 & 7)) * 8]);
            acc0 = __builtin_amdgcn_mfma_f32_32x32x16_bf16(ah, bh0, acc0, 0, 0, 0);
            acc1 = __builtin_amdgcn_mfma_f32_32x32x16_bf16(ah, bh1, acc1, 0, 0, 0);
            acc0 = __builtin_amdgcn_mfma_f32_32x32x16_bf16(ah, bl0, acc0, 0, 0, 0);
            acc1 = __builtin_amdgcn_mfma_f32_32x32x16_bf16(ah, bl1, acc1, 0, 0, 0);
            acc0 = __builtin_amdgcn_mfma_f32_32x32x16_bf16(al, bh0, acc0, 0, 0, 0);
            acc1 = __builtin_amdgcn_mfma_f32_32x32x16_bf16(al, bh1, acc1, 0, 0, 0);
        }
        __syncthreads();
    }

    // epilogue: C/D layout: col = lane&31, row = (r&3) + 8*(r>>2) + 4*(lane>>5)
    const int rbase = row0 + wid * 32;
    #pragma unroll
    for (int cb = 0; cb < 2; cb++) {
        const int colg = col0 + cb * 32 + l31;
        const float bcol = bias[colg];
        const float16v& acc = cb ? acc1 : acc0;
        #pragma unroll
        for (int r = 0; r < 16; r++) {
            int rowg = rbase + (r & 3) + 8 * (r >> 2) + 4 * kg;
            if (rowg < n) {
                float v = fmaxf(acc[r] + bcol, 0.0f);
                if (post) v *= post[rowg];
                Cb[(size_t)rowg * Dout + colg] = f2bf(v);
            }
        }
    }
}

// ---------------- classifier: out = h @ Wc + bc  (h is bf16, K=256, Dout=4) ----------------

__global__ __launch_bounds__(256) void classifier_kernel(
        const ushort* __restrict__ h, const float* __restrict__ Wc,
        const float* __restrict__ bc, float* __restrict__ out, int n) {
    __shared__ float Ws[256 * 4];
    int tid = threadIdx.x;
    for (int i = tid; i < 1024; i += 256) Ws[i] = Wc[i];
    __syncthreads();
    int node = blockIdx.x * 64 + (tid >> 2);
    int c = tid & 3;
    if (node < n) {
        float sum = bc[c];
        const ushort* hr = h + (size_t)node * 256;
        #pragma unroll
        for (int k0 = 0; k0 < 256; k0 += 8) {
            uint4 pk = *reinterpret_cast<const uint4*>(hr + k0);
            sum = fmaf(bf2f((ushort)(pk.x & 0xffff)), Ws[(k0 + 0) * 4 + c], sum);
            sum = fmaf(bf2f((ushort)(pk.x >> 16)),    Ws[(k0 + 1) * 4 + c], sum);
            sum = fmaf(bf2f((ushort)(pk.y & 0xffff)), Ws[(k0 + 2) * 4 + c], sum);
            sum = fmaf(bf2f((ushort)(pk.y >> 16)),    Ws[(k0 + 3) * 4 + c], sum);
            sum = fmaf(bf2f((ushort)(pk.z & 0xffff)), Ws[(k0 + 4) * 4 + c], sum);
            sum = fmaf(bf2f((ushort)(pk.z >> 16)),    Ws[(k0 + 5) * 4 + c], sum);
            sum = fmaf(bf2f((ushort)(pk.w & 0xffff)), Ws[(k0 + 6) * 4 + c], sum);
            sum = fmaf(bf2f((ushort)(pk.w >> 16)),    Ws[(k0 + 7) * 4 + c], sum);
        }
        out[(size_t)node * 4 + c] = sum;
    }
}

// ---------------- launch ----------------

extern "C" void kernel_launch(void* const* d_in, const int* in_sizes, int n_in,
                              void* d_out, int out_size, void* d_ws, size_t ws_size,
                              hipStream_t stream) {
    const float* x   = (const float*)d_in[0];
    const int*   src = (const int*)d_in[1];
    const int*   dst = (const int*)d_in[2];
    const float* W[4] = {(const float*)d_in[3], (const float*)d_in[5],
                         (const float*)d_in[7], (const float*)d_in[9]};
    const float* b[4] = {(const float*)d_in[4], (const float*)d_in[6],
                         (const float*)d_in[8], (const float*)d_in[10]};
    const float* Wc = (const float*)d_in[11];
    const float* bc = (const float*)d_in[12];
    float* out = (float*)d_out;

    // workspace layout (16B-aligned by construction)
    ushort* actB = (ushort*)d_ws;                        // N*256 ushort (bf16 activations, ns-scaled)
    ushort* Ah   = actB + (size_t)NN * 256;              // N*256 ushort (agg hi)
    ushort* Al   = Ah + (size_t)NN * 256;                // N*256 ushort (agg lo)
    float*  ns   = (float*)(Al + (size_t)NN * 256);      // N f32
    float*  nd   = ns + NN;                              // N f32
    ushort* Wth  = (ushort*)(nd + NN);                   // 256*256 ushort (W^T hi)
    ushort* Wtl  = Wth + 256 * 256;                      // 256*256 ushort (W^T lo)
    int*    rowptr  = (int*)(Wtl + 256 * 256);           // N+1 int
    int*    permSrc = rowptr + (NN + 1);                 // E int
    // transient scratch aliased into Ah (consumed before agg L0 writes Ah)
    int* degO   = (int*)Ah;
    int* degI   = degO + NN;
    int* cursor = degI + NN;
    int* bsum   = cursor + NN;
    (void)in_sizes; (void)n_in; (void)out_size; (void)ws_size;

    const int NB = (NN + SCAN_CHUNK - 1) / SCAN_CHUNK;

    // degrees + norms
    hipMemsetAsync(degO, 0, 2 * (size_t)NN * sizeof(int), stream);
    deg_kernel<<<(NEDGE + 255) / 256, 256, 0, stream>>>(src, dst, degO, degI, NEDGE);
    norm_kernel<<<(NN + 255) / 256, 256, 0, stream>>>(degO, degI, ns, nd, NN);

    // CSR build
    scan_reduce<<<NB, 256, 0, stream>>>(degI, bsum, NN);
    scan_bsums<<<1, 64, 0, stream>>>(bsum, NB);
    scan_final<<<NB, 256, 0, stream>>>(degI, bsum, rowptr, NN, NEDGE);
    copy_int<<<(NN + 255) / 256, 256, 0, stream>>>(rowptr, cursor, NN);
    scatter_kernel<<<(NEDGE + 255) / 256, 256, 0, stream>>>(src, dst, cursor, permSrc, NEDGE);

    // layer-0 gather payload: bf16(x * ns)
    convx_kernel<<<(NN * 32 + 255) / 256, 256, 0, stream>>>(x, ns, actB, NN);

    const int dims[5] = {128, 128, 128, 256, 256};

    for (int l = 0; l < 4; l++) {
        int K = dims[l], Dout = dims[l + 1];   // agg runs at width K (input side)
        int logD = (Dout == 128) ? 7 : 8;

        convw_kernel<<<((K << logD) + 255) / 256, 256, 0, stream>>>(W[l], Wth, Wtl, K, logD);

        // R = nd * agg(actB); hi/lo split for the GEMM
        int ablocks = (NN + 3) / 4;
        if (K == 128)
            agg_kernel<128><<<ablocks, 256, 0, stream>>>(actB, rowptr, permSrc, nd, Ah, Al, NN);
        else
            agg_kernel<256><<<ablocks, 256, 0, stream>>>(actB, rowptr, permSrc, nd, Ah, Al, NN);

        // actB' = bf16( relu(R@W + b) * (l<3 ? ns : 1) )
        const float* post = (l < 3) ? ns : nullptr;
        dim3 ggrid(Dout / 64, (NN + 127) / 128);
        gemm_mfma<<<ggrid, 256, 0, stream>>>(Ah, Al, Wth, Wtl, b[l], post, actB, NN, K, Dout);
    }

    classifier_kernel<<<(NN + 63) / 64, 256, 0, stream>>>(actB, Wc, bc, out, NN);
}

// Round 8
// 605.492 us; speedup vs baseline: 4.5354x; 1.0955x over previous
//
#include <hip/hip_runtime.h>
#include <cstdint>
#include <cstddef>

#define NN 100000
#define NEDGE 800000
#define SCAN_CHUNK 2048

typedef __attribute__((ext_vector_type(8))) short short8v;
typedef __attribute__((ext_vector_type(16))) float float16v;

__device__ inline ushort f2bf(float f) {
    uint32_t u = __float_as_uint(f);
    u += 0x7fff + ((u >> 16) & 1);   // round-to-nearest-even
    return (ushort)(u >> 16);
}
__device__ inline float bf2f(ushort h) { return __uint_as_float(((uint32_t)h) << 16); }
__device__ inline void split2(float a, ushort& h, ushort& l) {
    h = f2bf(a);
    l = f2bf(a - bf2f(h));
}

__device__ inline void gload16(const void* g, void* lds) {
    __builtin_amdgcn_global_load_lds(
        (const __attribute__((address_space(1))) void*)g,
        (__attribute__((address_space(3))) void*)lds, 16, 0, 0);
}

// ---------------- degree + norm ----------------

__global__ void deg_kernel(const int* __restrict__ src, const int* __restrict__ dst,
                           int* __restrict__ dOut, int* __restrict__ dIn, int E) {
    int i = blockIdx.x * blockDim.x + threadIdx.x;
    if (i < E) {
        atomicAdd(&dOut[src[i]], 1);
        atomicAdd(&dIn[dst[i]], 1);
    }
}

__global__ void norm_kernel(const int* __restrict__ dOut, const int* __restrict__ dIn,
                            float* __restrict__ ns, float* __restrict__ nd, int n) {
    int i = blockIdx.x * blockDim.x + threadIdx.x;
    if (i < n) {
        int a = dOut[i] > 1 ? dOut[i] : 1;
        int b = dIn[i] > 1 ? dIn[i] : 1;
        ns[i] = 1.0f / sqrtf((float)a);
        nd[i] = 1.0f / sqrtf((float)b);
    }
}

// ---------------- exclusive scan of in-degrees -> rowptr ----------------

__global__ void scan_reduce(const int* __restrict__ deg, int* __restrict__ bsum, int n) {
    __shared__ int sdata[256];
    int b = blockIdx.x, t = threadIdx.x;
    int base = b * SCAN_CHUNK;
    int sum = 0;
    for (int i = t; i < SCAN_CHUNK; i += 256) {
        int idx = base + i;
        if (idx < n) sum += deg[idx];
    }
    sdata[t] = sum;
    __syncthreads();
    for (int s = 128; s > 0; s >>= 1) {
        if (t < s) sdata[t] += sdata[t + s];
        __syncthreads();
    }
    if (t == 0) bsum[b] = sdata[0];
}

__global__ void scan_bsums(int* bsum, int nb) {
    if (threadIdx.x == 0 && blockIdx.x == 0) {
        int acc = 0;
        for (int i = 0; i < nb; i++) { int v = bsum[i]; bsum[i] = acc; acc += v; }
    }
}

__global__ void scan_final(const int* __restrict__ deg, const int* __restrict__ bsum,
                           int* __restrict__ rowptr, int n, int E) {
    __shared__ int tsum[256];
    int b = blockIdx.x, t = threadIdx.x;
    int base = b * SCAN_CHUNK;
    int loc[8];
    int s = 0;
    #pragma unroll
    for (int i = 0; i < 8; i++) {
        int idx = base + t * 8 + i;
        loc[i] = s;
        s += (idx < n) ? deg[idx] : 0;
    }
    tsum[t] = s;
    __syncthreads();
    for (int off = 1; off < 256; off <<= 1) {
        int v = (t >= off) ? tsum[t - off] : 0;
        __syncthreads();
        tsum[t] += v;
        __syncthreads();
    }
    int prefix = bsum[b] + (t > 0 ? tsum[t - 1] : 0);
    #pragma unroll
    for (int i = 0; i < 8; i++) {
        int idx = base + t * 8 + i;
        if (idx < n) rowptr[idx] = prefix + loc[i];
    }
    if (b == 0 && t == 0) rowptr[n] = E;
}

__global__ void copy_int(const int* __restrict__ a, int* __restrict__ b, int n) {
    int i = blockIdx.x * blockDim.x + threadIdx.x;
    if (i < n) b[i] = a[i];
}

__global__ void scatter_kernel(const int* __restrict__ src, const int* __restrict__ dst,
                               int* __restrict__ cursor, int* __restrict__ permSrc, int E) {
    int i = blockIdx.x * blockDim.x + threadIdx.x;
    if (i < E) {
        int p = atomicAdd(&cursor[dst[i]], 1);
        permSrc[p] = src[i];
    }
}

// ---------------- converters ----------------
__global__ void convx_kernel(const float* __restrict__ x, const float* __restrict__ ns,
                             ushort* __restrict__ actB, int n) {
    int idx = blockIdx.x * blockDim.x + threadIdx.x;   // float4 units
    if (idx >= n * 32) return;
    int node = idx >> 5;
    int f0 = (idx & 31) * 4;
    float sc = ns[node];
    float4 v = *reinterpret_cast<const float4*>(x + (size_t)node * 128 + f0);
    ushort4 h;
    h.x = f2bf(v.x * sc);
    h.y = f2bf(v.y * sc);
    h.z = f2bf(v.z * sc);
    h.w = f2bf(v.w * sc);
    *reinterpret_cast<ushort4*>(actB + (size_t)node * 128 + f0) = h;
}

__global__ void convw_kernel(const float* __restrict__ W, ushort* __restrict__ Bh,
                             ushort* __restrict__ Bl, int K, int logD) {
    int idx = blockIdx.x * blockDim.x + threadIdx.x;
    if (idx >= (K << logD)) return;
    int k = idx >> logD;
    int d = idx & ((1 << logD) - 1);
    ushort h, l;
    split2(W[idx], h, l);
    Bh[(size_t)d * K + k] = h;
    Bl[(size_t)d * K + k] = l;
}

// ---------------- CSR aggregation: 16B gather loads, edge-group MLP ----------------

__device__ inline void accum8(float* a, uint4 v) {
    a[0] += __uint_as_float(v.x << 16);
    a[1] += __uint_as_float(v.x & 0xffff0000u);
    a[2] += __uint_as_float(v.y << 16);
    a[3] += __uint_as_float(v.y & 0xffff0000u);
    a[4] += __uint_as_float(v.z << 16);
    a[5] += __uint_as_float(v.z & 0xffff0000u);
    a[6] += __uint_as_float(v.w << 16);
    a[7] += __uint_as_float(v.w & 0xffff0000u);
}

template<int D>
__global__ __launch_bounds__(256) void agg_kernel(
        const ushort* __restrict__ act, const int* __restrict__ rowptr,
        const int* __restrict__ permSrc, const float* __restrict__ nd,
        ushort* __restrict__ outH, ushort* __restrict__ outL, int n) {
    int node = blockIdx.x * 4 + (threadIdx.x >> 6);
    if (node >= n) return;
    int lane = threadIdx.x & 63;
    constexpr int GROUPS = (D == 256) ? 2 : 4;   // edge slices per wave
    constexpr int GL = 64 / GROUPS;              // lanes per slice (32 / 16)
    const int g  = lane / GL;
    const int gl = lane % GL;
    const int f0 = gl * 8;                       // 8 bf16 per lane (16B)
    float a[8] = {0.f,0.f,0.f,0.f,0.f,0.f,0.f,0.f};
    int r0 = rowptr[node], r1 = rowptr[node + 1];

    int e = r0 + g;
    for (; e + 3 * GROUPS < r1; e += 4 * GROUPS) {
        int s0 = permSrc[e];
        int s1 = permSrc[e + GROUPS];
        int s2 = permSrc[e + 2 * GROUPS];
        int s3 = permSrc[e + 3 * GROUPS];
        uint4 v0 = *reinterpret_cast<const uint4*>(act + (size_t)s0 * D + f0);
        uint4 v1 = *reinterpret_cast<const uint4*>(act + (size_t)s1 * D + f0);
        uint4 v2 = *reinterpret_cast<const uint4*>(act + (size_t)s2 * D + f0);
        uint4 v3 = *reinterpret_cast<const uint4*>(act + (size_t)s3 * D + f0);
        accum8(a, v0); accum8(a, v1); accum8(a, v2); accum8(a, v3);
    }
    for (; e < r1; e += GROUPS) {
        int s = permSrc[e];
        accum8(a, *reinterpret_cast<const uint4*>(act + (size_t)s * D + f0));
    }

    #pragma unroll
    for (int j = 0; j < 8; j++) {
        if constexpr (GROUPS == 4) a[j] += __shfl_xor(a[j], 16);
        a[j] += __shfl_xor(a[j], 32);
    }

    if (g == 0) {
        float sc = nd[node];
        union { ushort u[8]; uint4 v; } H, L;
        #pragma unroll
        for (int j = 0; j < 8; j++) split2(a[j] * sc, H.u[j], L.u[j]);
        *reinterpret_cast<uint4*>(outH + (size_t)node * D + f0) = H.v;
        *reinterpret_cast<uint4*>(outL + (size_t)node * D + f0) = L.v;
    }
}

// ---------------- MFMA GEMM with fused epilogue ----------------
// Cb[n][Dout] = bf16( relu( (Ahi+Alo)@(Bhi+Blo)^T + bias ) * (post ? post[row] : 1) )
// 128x64 tile, 4 waves (wave = 32 rows x 64 cols).
// XCD co-location: xcd = bid&7, t = bid>>3, cb = t&(CB-1), rowpanel = (t>>logCB)*8+xcd
// -> the CB col-blocks of one row panel land on the same XCD (L2 reuse of A).
// Staging via global_load_lds (linear LDS dest, pre-swizzled per-lane global src);
// 16B-chunk XOR swizzle ch ^= (r&7) applied on source and on ds_read.

__global__ __launch_bounds__(256) void gemm_mfma(
        const ushort* __restrict__ Ahi, const ushort* __restrict__ Alo,
        const ushort* __restrict__ Bhi, const ushort* __restrict__ Blo,
        const float* __restrict__ bias, const float* __restrict__ post,
        ushort* __restrict__ Cb, int n, int K, int Dout, int logCB, int nrowp) {
    __shared__ __align__(16) ushort sAh[128][64];
    __shared__ __align__(16) ushort sAl[128][64];
    __shared__ __align__(16) ushort sBh[64][64];
    __shared__ __align__(16) ushort sBl[64][64];
    const int tid = threadIdx.x;
    const int lane = tid & 63;
    const int wid = tid >> 6;
    const int l31 = lane & 31;
    const int kg = lane >> 5;         // k-group (0/1)

    // XCD co-location decode
    const int bid = blockIdx.x;
    const int xcd = bid & 7;
    const int t = bid >> 3;
    const int cb2 = t & ((1 << logCB) - 1);
    const int rp = (t >> logCB) * 8 + xcd;
    if (rp >= nrowp) return;
    const int row0 = rp * 128;
    const int col0 = cb2 * 64;

    // precompute per-issue global bases (k0-invariant) and uniform LDS bases
    const ushort* gAh[4]; const ushort* gAl[4];
    char* lA[4];
    #pragma unroll
    for (int i = 0; i < 4; i++) {
        int slot = i * 256 + wid * 64 + lane;
        int r = slot >> 3, ch = slot & 7;
        int gch = ch ^ (r & 7);
        int row = row0 + r; if (row >= n) row = n - 1;   // clamp: dup rows feed discarded C rows
        gAh[i] = Ahi + (size_t)row * K + gch * 8;
        gAl[i] = Alo + (size_t)row * K + gch * 8;
        lA[i] = (char*)&sAh[0][0] + (size_t)(i * 256 + wid * 64) * 16;  // uniform per wave
    }
    const ushort* gBh[2]; const ushort* gBl[2];
    char* lB[2];
    #pragma unroll
    for (int i = 0; i < 2; i++) {
        int slot = i * 256 + wid * 64 + lane;
        int r = slot >> 3, ch = slot & 7;
        int gch = ch ^ (r & 7);
        gBh[i] = Bhi + (size_t)(col0 + r) * K + gch * 8;
        gBl[i] = Blo + (size_t)(col0 + r) * K + gch * 8;
        lB[i] = (char*)&sBh[0][0] + (size_t)(i * 256 + wid * 64) * 16;
    }
    const size_t lalo = (char*)&sAl[0][0] - (char*)&sAh[0][0];
    const size_t lblo = (char*)&sBl[0][0] - (char*)&sBh[0][0];

    float16v acc0 = {0.f,0.f,0.f,0.f,0.f,0.f,0.f,0.f,0.f,0.f,0.f,0.f,0.f,0.f,0.f,0.f};
    float16v acc1 = {0.f,0.f,0.f,0.f,0.f,0.f,0.f,0.f,0.f,0.f,0.f,0.f,0.f,0.f,0.f,0.f};

    for (int k0 = 0; k0 < K; k0 += 64) {
        #pragma unroll
        for (int i = 0; i < 4; i++) {
            gload16(gAh[i] + k0, lA[i]);
            gload16(gAl[i] + k0, lA[i] + lalo);
        }
        #pragma unroll
        for (int i = 0; i < 2; i++) {
            gload16(gBh[i] + k0, lB[i]);
            gload16(gBl[i] + k0, lB[i] + lblo);
        }
        __syncthreads();

        #pragma unroll
        for (int ks = 0; ks < 4; ks++) {
            const int gw = ks * 2 + kg;          // wanted global chunk
            const int rA = wid * 32 + l31;
            const int rB0 = l31, rB1 = 32 + l31;
            short8v ah = *reinterpret_cast<const short8v*>(&sAh[rA][(gw ^ (rA & 7)) * 8]);
            short8v al = *reinterpret_cast<const short8v*>(&sAl[rA][(gw ^ (rA & 7)) * 8]);
            short8v bh0 = *reinterpret_cast<const short8v*>(&sBh[rB0][(gw ^ (rB0 & 7)) * 8]);
            short8v bl0 = *reinterpret_cast<const short8v*>(&sBl[rB0][(gw ^ (rB0 & 7)) * 8]);
            short8v bh1 = *reinterpret_cast<const short8v*>(&sBh[rB1][(gw ^ (rB1 & 7)) * 8]);
            short8v bl1 = *reinterpret_cast<const short8v*>(&sBl[rB1][(gw ^ (rB1 & 7)) * 8]);
            acc0 = __builtin_amdgcn_mfma_f32_32x32x16_bf16(ah, bh0, acc0, 0, 0, 0);
            acc1 = __builtin_amdgcn_mfma_f32_32x32x16_bf16(ah, bh1, acc1, 0, 0, 0);
            acc0 = __builtin_amdgcn_mfma_f32_32x32x16_bf16(ah, bl0, acc0, 0, 0, 0);
            acc1 = __builtin_amdgcn_mfma_f32_32x32x16_bf16(ah, bl1, acc1, 0, 0, 0);
            acc0 = __builtin_amdgcn_mfma_f32_32x32x16_bf16(al, bh0, acc0, 0, 0, 0);
            acc1 = __builtin_amdgcn_mfma_f32_32x32x16_bf16(al, bh1, acc1, 0, 0, 0);
        }
        __syncthreads();
    }

    // epilogue: C/D layout: col = lane&31, row = (r&3) + 8*(r>>2) + 4*(lane>>5)
    const int rbase = row0 + wid * 32;
    #pragma unroll
    for (int cb = 0; cb < 2; cb++) {
        const int colg = col0 + cb * 32 + l31;
        const float bcol = bias[colg];
        const float16v& acc = cb ? acc1 : acc0;
        #pragma unroll
        for (int r = 0; r < 16; r++) {
            int rowg = rbase + (r & 3) + 8 * (r >> 2) + 4 * kg;
            if (rowg < n) {
                float v = fmaxf(acc[r] + bcol, 0.0f);
                if (post) v *= post[rowg];
                Cb[(size_t)rowg * Dout + colg] = f2bf(v);
            }
        }
    }
}

// ---------------- classifier: out = h @ Wc + bc  (h is bf16, K=256, Dout=4) ----------------

__global__ __launch_bounds__(256) void classifier_kernel(
        const ushort* __restrict__ h, const float* __restrict__ Wc,
        const float* __restrict__ bc, float* __restrict__ out, int n) {
    __shared__ float Ws[256 * 4];
    int tid = threadIdx.x;
    for (int i = tid; i < 1024; i += 256) Ws[i] = Wc[i];
    __syncthreads();
    int node = blockIdx.x * 64 + (tid >> 2);
    int c = tid & 3;
    if (node < n) {
        float sum = bc[c];
        const ushort* hr = h + (size_t)node * 256;
        #pragma unroll
        for (int k0 = 0; k0 < 256; k0 += 8) {
            uint4 pk = *reinterpret_cast<const uint4*>(hr + k0);
            sum = fmaf(bf2f((ushort)(pk.x & 0xffff)), Ws[(k0 + 0) * 4 + c], sum);
            sum = fmaf(bf2f((ushort)(pk.x >> 16)),    Ws[(k0 + 1) * 4 + c], sum);
            sum = fmaf(bf2f((ushort)(pk.y & 0xffff)), Ws[(k0 + 2) * 4 + c], sum);
            sum = fmaf(bf2f((ushort)(pk.y >> 16)),    Ws[(k0 + 3) * 4 + c], sum);
            sum = fmaf(bf2f((ushort)(pk.z & 0xffff)), Ws[(k0 + 4) * 4 + c], sum);
            sum = fmaf(bf2f((ushort)(pk.z >> 16)),    Ws[(k0 + 5) * 4 + c], sum);
            sum = fmaf(bf2f((ushort)(pk.w & 0xffff)), Ws[(k0 + 6) * 4 + c], sum);
            sum = fmaf(bf2f((ushort)(pk.w >> 16)),    Ws[(k0 + 7) * 4 + c], sum);
        }
        out[(size_t)node * 4 + c] = sum;
    }
}

// ---------------- launch ----------------

extern "C" void kernel_launch(void* const* d_in, const int* in_sizes, int n_in,
                              void* d_out, int out_size, void* d_ws, size_t ws_size,
                              hipStream_t stream) {
    const float* x   = (const float*)d_in[0];
    const int*   src = (const int*)d_in[1];
    const int*   dst = (const int*)d_in[2];
    const float* W[4] = {(const float*)d_in[3], (const float*)d_in[5],
                         (const float*)d_in[7], (const float*)d_in[9]};
    const float* b[4] = {(const float*)d_in[4], (const float*)d_in[6],
                         (const float*)d_in[8], (const float*)d_in[10]};
    const float* Wc = (const float*)d_in[11];
    const float* bc = (const float*)d_in[12];
    float* out = (float*)d_out;

    // workspace layout (16B-aligned by construction)
    ushort* actB = (ushort*)d_ws;                        // N*256 ushort (bf16 activations, ns-scaled)
    ushort* Ah   = actB + (size_t)NN * 256;              // N*256 ushort (agg hi)
    ushort* Al   = Ah + (size_t)NN * 256;                // N*256 ushort (agg lo)
    float*  ns   = (float*)(Al + (size_t)NN * 256);      // N f32
    float*  nd   = ns + NN;                              // N f32
    ushort* Wth  = (ushort*)(nd + NN);                   // 256*256 ushort (W^T hi)
    ushort* Wtl  = Wth + 256 * 256;                      // 256*256 ushort (W^T lo)
    int*    rowptr  = (int*)(Wtl + 256 * 256);           // N+1 int
    int*    permSrc = rowptr + (NN + 1);                 // E int
    // transient scratch aliased into Ah (consumed before agg L0 writes Ah)
    int* degO   = (int*)Ah;
    int* degI   = degO + NN;
    int* cursor = degI + NN;
    int* bsum   = cursor + NN;
    (void)in_sizes; (void)n_in; (void)out_size; (void)ws_size;

    const int NB = (NN + SCAN_CHUNK - 1) / SCAN_CHUNK;

    // degrees + norms
    hipMemsetAsync(degO, 0, 2 * (size_t)NN * sizeof(int), stream);
    deg_kernel<<<(NEDGE + 255) / 256, 256, 0, stream>>>(src, dst, degO, degI, NEDGE);
    norm_kernel<<<(NN + 255) / 256, 256, 0, stream>>>(degO, degI, ns, nd, NN);

    // CSR build
    scan_reduce<<<NB, 256, 0, stream>>>(degI, bsum, NN);
    scan_bsums<<<1, 64, 0, stream>>>(bsum, NB);
    scan_final<<<NB, 256, 0, stream>>>(degI, bsum, rowptr, NN, NEDGE);
    copy_int<<<(NN + 255) / 256, 256, 0, stream>>>(rowptr, cursor, NN);
    scatter_kernel<<<(NEDGE + 255) / 256, 256, 0, stream>>>(src, dst, cursor, permSrc, NEDGE);

    // layer-0 gather payload: bf16(x * ns)
    convx_kernel<<<(NN * 32 + 255) / 256, 256, 0, stream>>>(x, ns, actB, NN);

    const int dims[5] = {128, 128, 128, 256, 256};
    const int nrowp = (NN + 127) / 128;
    const int nrowp8 = ((nrowp + 7) / 8) * 8;

    for (int l = 0; l < 4; l++) {
        int K = dims[l], Dout = dims[l + 1];   // agg runs at width K (input side)
        int logD = (Dout == 128) ? 7 : 8;
        int logCB = (Dout == 128) ? 1 : 2;
        int CB = Dout / 64;

        convw_kernel<<<((K << logD) + 255) / 256, 256, 0, stream>>>(W[l], Wth, Wtl, K, logD);

        // R = nd * agg(actB); hi/lo split for the GEMM
        int ablocks = (NN + 3) / 4;
        if (K == 128)
            agg_kernel<128><<<ablocks, 256, 0, stream>>>(actB, rowptr, permSrc, nd, Ah, Al, NN);
        else
            agg_kernel<256><<<ablocks, 256, 0, stream>>>(actB, rowptr, permSrc, nd, Ah, Al, NN);

        // actB' = bf16( relu(R@W + b) * (l<3 ? ns : 1) )
        const float* post = (l < 3) ? ns : nullptr;
        gemm_mfma<<<nrowp8 * CB, 256, 0, stream>>>(Ah, Al, Wth, Wtl, b[l], post, actB,
                                                   NN, K, Dout, logCB, nrowp);
    }

    classifier_kernel<<<(NN + 63) / 64, 256, 0, stream>>>(actB, Wc, bc, out, NN);
}

// Round 9
// 524.780 us; speedup vs baseline: 5.2330x; 1.1538x over previous
//
#include <hip/hip_runtime.h>
#include <cstdint>
#include <cstddef>

#define NN 100000
#define NEDGE 800000
#define SCAN_CHUNK 2048

typedef __attribute__((ext_vector_type(8))) short short8v;
typedef __attribute__((ext_vector_type(16))) float float16v;

__device__ inline ushort f2bf(float f) {
    uint32_t u = __float_as_uint(f);
    u += 0x7fff + ((u >> 16) & 1);   // round-to-nearest-even
    return (ushort)(u >> 16);
}
__device__ inline float bf2f(ushort h) { return __uint_as_float(((uint32_t)h) << 16); }
__device__ inline void split2(float a, ushort& h, ushort& l) {
    h = f2bf(a);
    l = f2bf(a - bf2f(h));
}

__device__ inline void gload16(const void* g, void* lds) {
    __builtin_amdgcn_global_load_lds(
        (const __attribute__((address_space(1))) void*)g,
        (__attribute__((address_space(3))) void*)lds, 16, 0, 0);
}

// ---------------- degree + norm ----------------

__global__ void deg_kernel(const int* __restrict__ src, const int* __restrict__ dst,
                           int* __restrict__ dOut, int* __restrict__ dIn, int E) {
    int i = blockIdx.x * blockDim.x + threadIdx.x;
    if (i < E) {
        atomicAdd(&dOut[src[i]], 1);
        atomicAdd(&dIn[dst[i]], 1);
    }
}

__global__ void norm_kernel(const int* __restrict__ dOut, const int* __restrict__ dIn,
                            float* __restrict__ ns, float* __restrict__ nd, int n) {
    int i = blockIdx.x * blockDim.x + threadIdx.x;
    if (i < n) {
        int a = dOut[i] > 1 ? dOut[i] : 1;
        int b = dIn[i] > 1 ? dIn[i] : 1;
        ns[i] = 1.0f / sqrtf((float)a);
        nd[i] = 1.0f / sqrtf((float)b);
    }
}

// ---------------- exclusive scan of in-degrees -> rowptr (+cursor copy) ----------------

__global__ void scan_reduce(const int* __restrict__ deg, int* __restrict__ bsum, int n) {
    __shared__ int sdata[256];
    int b = blockIdx.x, t = threadIdx.x;
    int base = b * SCAN_CHUNK;
    int sum = 0;
    for (int i = t; i < SCAN_CHUNK; i += 256) {
        int idx = base + i;
        if (idx < n) sum += deg[idx];
    }
    sdata[t] = sum;
    __syncthreads();
    for (int s = 128; s > 0; s >>= 1) {
        if (t < s) sdata[t] += sdata[t + s];
        __syncthreads();
    }
    if (t == 0) bsum[b] = sdata[0];
}

__global__ void scan_bsums(int* bsum, int nb) {
    if (threadIdx.x == 0 && blockIdx.x == 0) {
        int acc = 0;
        for (int i = 0; i < nb; i++) { int v = bsum[i]; bsum[i] = acc; acc += v; }
    }
}

__global__ void scan_final(const int* __restrict__ deg, const int* __restrict__ bsum,
                           int* __restrict__ rowptr, int* __restrict__ cursor, int n, int E) {
    __shared__ int tsum[256];
    int b = blockIdx.x, t = threadIdx.x;
    int base = b * SCAN_CHUNK;
    int loc[8];
    int s = 0;
    #pragma unroll
    for (int i = 0; i < 8; i++) {
        int idx = base + t * 8 + i;
        loc[i] = s;
        s += (idx < n) ? deg[idx] : 0;
    }
    tsum[t] = s;
    __syncthreads();
    for (int off = 1; off < 256; off <<= 1) {
        int v = (t >= off) ? tsum[t - off] : 0;
        __syncthreads();
        tsum[t] += v;
        __syncthreads();
    }
    int prefix = bsum[b] + (t > 0 ? tsum[t - 1] : 0);
    #pragma unroll
    for (int i = 0; i < 8; i++) {
        int idx = base + t * 8 + i;
        if (idx < n) {
            rowptr[idx] = prefix + loc[i];
            cursor[idx] = prefix + loc[i];
        }
    }
    if (b == 0 && t == 0) rowptr[n] = E;
}

__global__ void scatter_kernel(const int* __restrict__ src, const int* __restrict__ dst,
                               int* __restrict__ cursor, int* __restrict__ permSrc, int E) {
    int i = blockIdx.x * blockDim.x + threadIdx.x;
    if (i < E) {
        int p = atomicAdd(&cursor[dst[i]], 1);
        permSrc[p] = src[i];
    }
}

// ---------------- converters ----------------
__global__ void convx_kernel(const float* __restrict__ x, const float* __restrict__ ns,
                             ushort* __restrict__ actB, int n) {
    int idx = blockIdx.x * blockDim.x + threadIdx.x;   // float4 units
    if (idx >= n * 32) return;
    int node = idx >> 5;
    int f0 = (idx & 31) * 4;
    float sc = ns[node];
    float4 v = *reinterpret_cast<const float4*>(x + (size_t)node * 128 + f0);
    ushort4 h;
    h.x = f2bf(v.x * sc);
    h.y = f2bf(v.y * sc);
    h.z = f2bf(v.z * sc);
    h.w = f2bf(v.w * sc);
    *reinterpret_cast<ushort4*>(actB + (size_t)node * 128 + f0) = h;
}

__global__ void convw_kernel(const float* __restrict__ W, ushort* __restrict__ Bh,
                             ushort* __restrict__ Bl, int K, int logD) {
    int idx = blockIdx.x * blockDim.x + threadIdx.x;
    if (idx >= (K << logD)) return;
    int k = idx >> logD;
    int d = idx & ((1 << logD) - 1);
    ushort h, l;
    split2(W[idx], h, l);
    Bh[(size_t)d * K + k] = h;
    Bl[(size_t)d * K + k] = l;
}

// ---------------- CSR aggregation: 16B gather loads, edge-group MLP ----------------
// Rb[node] = bf16( nd[node] * sum_{e in CSR(node)} act[src[e]] )

__device__ inline void accum8(float* a, uint4 v) {
    a[0] += __uint_as_float(v.x << 16);
    a[1] += __uint_as_float(v.x & 0xffff0000u);
    a[2] += __uint_as_float(v.y << 16);
    a[3] += __uint_as_float(v.y & 0xffff0000u);
    a[4] += __uint_as_float(v.z << 16);
    a[5] += __uint_as_float(v.z & 0xffff0000u);
    a[6] += __uint_as_float(v.w << 16);
    a[7] += __uint_as_float(v.w & 0xffff0000u);
}

template<int D>
__global__ __launch_bounds__(256) void agg_kernel(
        const ushort* __restrict__ act, const int* __restrict__ rowptr,
        const int* __restrict__ permSrc, const float* __restrict__ nd,
        ushort* __restrict__ Rb, int n) {
    int node = blockIdx.x * 4 + (threadIdx.x >> 6);
    if (node >= n) return;
    int lane = threadIdx.x & 63;
    constexpr int GROUPS = (D == 256) ? 2 : 4;   // edge slices per wave
    constexpr int GL = 64 / GROUPS;              // lanes per slice (32 / 16)
    const int g  = lane / GL;
    const int gl = lane % GL;
    const int f0 = gl * 8;                       // 8 bf16 per lane (16B)
    float a[8] = {0.f,0.f,0.f,0.f,0.f,0.f,0.f,0.f};
    int r0 = rowptr[node], r1 = rowptr[node + 1];

    int e = r0 + g;
    for (; e + 3 * GROUPS < r1; e += 4 * GROUPS) {
        int s0 = permSrc[e];
        int s1 = permSrc[e + GROUPS];
        int s2 = permSrc[e + 2 * GROUPS];
        int s3 = permSrc[e + 3 * GROUPS];
        uint4 v0 = *reinterpret_cast<const uint4*>(act + (size_t)s0 * D + f0);
        uint4 v1 = *reinterpret_cast<const uint4*>(act + (size_t)s1 * D + f0);
        uint4 v2 = *reinterpret_cast<const uint4*>(act + (size_t)s2 * D + f0);
        uint4 v3 = *reinterpret_cast<const uint4*>(act + (size_t)s3 * D + f0);
        accum8(a, v0); accum8(a, v1); accum8(a, v2); accum8(a, v3);
    }
    for (; e < r1; e += GROUPS) {
        int s = permSrc[e];
        accum8(a, *reinterpret_cast<const uint4*>(act + (size_t)s * D + f0));
    }

    #pragma unroll
    for (int j = 0; j < 8; j++) {
        if constexpr (GROUPS == 4) a[j] += __shfl_xor(a[j], 16);
        a[j] += __shfl_xor(a[j], 32);
    }

    if (g == 0) {
        float sc = nd[node];
        union { ushort u[8]; uint4 v; } H;
        #pragma unroll
        for (int j = 0; j < 8; j++) H.u[j] = f2bf(a[j] * sc);
        *reinterpret_cast<uint4*>(Rb + (size_t)node * D + f0) = H.v;
    }
}

// ---------------- MFMA GEMM with fused epilogue ----------------
// Cb[n][Dout] = bf16( relu( A@(Bhi+Blo)^T + bias ) * (post ? post[row] : 1) )
// A plain bf16; W split hi/lo. 128x64 tile, 4 waves.
// XCD co-location + global_load_lds staging + 16B-chunk XOR swizzle.

__global__ __launch_bounds__(256) void gemm_mfma(
        const ushort* __restrict__ A,
        const ushort* __restrict__ Bhi, const ushort* __restrict__ Blo,
        const float* __restrict__ bias, const float* __restrict__ post,
        ushort* __restrict__ Cb, int n, int K, int Dout, int logCB, int nrowp) {
    __shared__ __align__(16) ushort sA[128][64];
    __shared__ __align__(16) ushort sBh[64][64];
    __shared__ __align__(16) ushort sBl[64][64];
    const int tid = threadIdx.x;
    const int lane = tid & 63;
    const int wid = tid >> 6;
    const int l31 = lane & 31;
    const int kg = lane >> 5;         // k-group (0/1)

    // XCD co-location decode
    const int bid = blockIdx.x;
    const int xcd = bid & 7;
    const int t = bid >> 3;
    const int cb2 = t & ((1 << logCB) - 1);
    const int rp = (t >> logCB) * 8 + xcd;
    if (rp >= nrowp) return;
    const int row0 = rp * 128;
    const int col0 = cb2 * 64;

    // precompute per-issue global bases (k0-invariant) and uniform LDS bases
    const ushort* gA[4];
    char* lA[4];
    #pragma unroll
    for (int i = 0; i < 4; i++) {
        int slot = i * 256 + wid * 64 + lane;
        int r = slot >> 3, ch = slot & 7;
        int gch = ch ^ (r & 7);
        int row = row0 + r; if (row >= n) row = n - 1;   // clamp: dup rows feed discarded C rows
        gA[i] = A + (size_t)row * K + gch * 8;
        lA[i] = (char*)&sA[0][0] + (size_t)(i * 256 + wid * 64) * 16;  // uniform per wave
    }
    const ushort* gBh[2]; const ushort* gBl[2];
    char* lB[2];
    #pragma unroll
    for (int i = 0; i < 2; i++) {
        int slot = i * 256 + wid * 64 + lane;
        int r = slot >> 3, ch = slot & 7;
        int gch = ch ^ (r & 7);
        gBh[i] = Bhi + (size_t)(col0 + r) * K + gch * 8;
        gBl[i] = Blo + (size_t)(col0 + r) * K + gch * 8;
        lB[i] = (char*)&sBh[0][0] + (size_t)(i * 256 + wid * 64) * 16;
    }
    const size_t lblo = (char*)&sBl[0][0] - (char*)&sBh[0][0];

    float16v acc0 = {0.f,0.f,0.f,0.f,0.f,0.f,0.f,0.f,0.f,0.f,0.f,0.f,0.f,0.f,0.f,0.f};
    float16v acc1 = {0.f,0.f,0.f,0.f,0.f,0.f,0.f,0.f,0.f,0.f,0.f,0.f,0.f,0.f,0.f,0.f};

    for (int k0 = 0; k0 < K; k0 += 64) {
        #pragma unroll
        for (int i = 0; i < 4; i++) gload16(gA[i] + k0, lA[i]);
        #pragma unroll
        for (int i = 0; i < 2; i++) {
            gload16(gBh[i] + k0, lB[i]);
            gload16(gBl[i] + k0, lB[i] + lblo);
        }
        __syncthreads();

        #pragma unroll
        for (int ks = 0; ks < 4; ks++) {
            const int gw = ks * 2 + kg;          // wanted global chunk
            const int rA = wid * 32 + l31;
            const int rB0 = l31, rB1 = 32 + l31;
            short8v a = *reinterpret_cast<const short8v*>(&sA[rA][(gw ^ (rA & 7)) * 8]);
            short8v bh0 = *reinterpret_cast<const short8v*>(&sBh[rB0][(gw ^ (rB0 & 7)) * 8]);
            short8v bl0 = *reinterpret_cast<const short8v*>(&sBl[rB0][(gw ^ (rB0 & 7)) * 8]);
            short8v bh1 = *reinterpret_cast<const short8v*>(&sBh[rB1][(gw ^ (rB1 & 7)) * 8]);
            short8v bl1 = *reinterpret_cast<const short8v*>(&sBl[rB1][(gw ^ (rB1 & 7)) * 8]);
            acc0 = __builtin_amdgcn_mfma_f32_32x32x16_bf16(a, bh0, acc0, 0, 0, 0);
            acc1 = __builtin_amdgcn_mfma_f32_32x32x16_bf16(a, bh1, acc1, 0, 0, 0);
            acc0 = __builtin_amdgcn_mfma_f32_32x32x16_bf16(a, bl0, acc0, 0, 0, 0);
            acc1 = __builtin_amdgcn_mfma_f32_32x32x16_bf16(a, bl1, acc1, 0, 0, 0);
        }
        __syncthreads();
    }

    // epilogue: C/D layout: col = lane&31, row = (r&3) + 8*(r>>2) + 4*(lane>>5)
    const int rbase = row0 + wid * 32;
    #pragma unroll
    for (int cb = 0; cb < 2; cb++) {
        const int colg = col0 + cb * 32 + l31;
        const float bcol = bias[colg];
        const float16v& acc = cb ? acc1 : acc0;
        #pragma unroll
        for (int r = 0; r < 16; r++) {
            int rowg = rbase + (r & 3) + 8 * (r >> 2) + 4 * kg;
            if (rowg < n) {
                float v = fmaxf(acc[r] + bcol, 0.0f);
                if (post) v *= post[rowg];
                Cb[(size_t)rowg * Dout + colg] = f2bf(v);
            }
        }
    }
}

// ---------------- classifier: out = h @ Wc + bc  (h is bf16, K=256, Dout=4) ----------------

__global__ __launch_bounds__(256) void classifier_kernel(
        const ushort* __restrict__ h, const float* __restrict__ Wc,
        const float* __restrict__ bc, float* __restrict__ out, int n) {
    __shared__ float Ws[256 * 4];
    int tid = threadIdx.x;
    for (int i = tid; i < 1024; i += 256) Ws[i] = Wc[i];
    __syncthreads();
    int node = blockIdx.x * 64 + (tid >> 2);
    int c = tid & 3;
    if (node < n) {
        float sum = bc[c];
        const ushort* hr = h + (size_t)node * 256;
        #pragma unroll
        for (int k0 = 0; k0 < 256; k0 += 8) {
            uint4 pk = *reinterpret_cast<const uint4*>(hr + k0);
            sum = fmaf(bf2f((ushort)(pk.x & 0xffff)), Ws[(k0 + 0) * 4 + c], sum);
            sum = fmaf(bf2f((ushort)(pk.x >> 16)),    Ws[(k0 + 1) * 4 + c], sum);
            sum = fmaf(bf2f((ushort)(pk.y & 0xffff)), Ws[(k0 + 2) * 4 + c], sum);
            sum = fmaf(bf2f((ushort)(pk.y >> 16)),    Ws[(k0 + 3) * 4 + c], sum);
            sum = fmaf(bf2f((ushort)(pk.z & 0xffff)), Ws[(k0 + 4) * 4 + c], sum);
            sum = fmaf(bf2f((ushort)(pk.z >> 16)),    Ws[(k0 + 5) * 4 + c], sum);
            sum = fmaf(bf2f((ushort)(pk.w & 0xffff)), Ws[(k0 + 6) * 4 + c], sum);
            sum = fmaf(bf2f((ushort)(pk.w >> 16)),    Ws[(k0 + 7) * 4 + c], sum);
        }
        out[(size_t)node * 4 + c] = sum;
    }
}

// ---------------- launch ----------------

extern "C" void kernel_launch(void* const* d_in, const int* in_sizes, int n_in,
                              void* d_out, int out_size, void* d_ws, size_t ws_size,
                              hipStream_t stream) {
    const float* x   = (const float*)d_in[0];
    const int*   src = (const int*)d_in[1];
    const int*   dst = (const int*)d_in[2];
    const float* W[4] = {(const float*)d_in[3], (const float*)d_in[5],
                         (const float*)d_in[7], (const float*)d_in[9]};
    const float* b[4] = {(const float*)d_in[4], (const float*)d_in[6],
                         (const float*)d_in[8], (const float*)d_in[10]};
    const float* Wc = (const float*)d_in[11];
    const float* bc = (const float*)d_in[12];
    float* out = (float*)d_out;

    // workspace layout (16B-aligned by construction)
    ushort* actB = (ushort*)d_ws;                        // N*256 ushort (bf16 activations, ns-scaled)
    ushort* Rb   = actB + (size_t)NN * 256;              // N*256 ushort (bf16 aggregated, nd-scaled)
    float*  ns   = (float*)(Rb + (size_t)NN * 256);      // N f32
    float*  nd   = ns + NN;                              // N f32
    ushort* Wth  = (ushort*)(nd + NN);                   // 256*256 ushort (W^T hi)
    ushort* Wtl  = Wth + 256 * 256;                      // 256*256 ushort (W^T lo)
    int*    rowptr  = (int*)(Wtl + 256 * 256);           // N+1 int
    int*    permSrc = rowptr + (NN + 1);                 // E int
    int*    cursor  = permSrc + NEDGE;                   // N int (persists through scatter)
    // transient scratch aliased into Rb (consumed before first agg writes Rb)
    int* degO = (int*)Rb;
    int* degI = degO + NN;
    int* bsum = degI + NN;
    (void)in_sizes; (void)n_in; (void)out_size; (void)ws_size;

    const int NB = (NN + SCAN_CHUNK - 1) / SCAN_CHUNK;

    // degrees + norms
    hipMemsetAsync(degO, 0, 2 * (size_t)NN * sizeof(int), stream);
    deg_kernel<<<(NEDGE + 255) / 256, 256, 0, stream>>>(src, dst, degO, degI, NEDGE);
    norm_kernel<<<(NN + 255) / 256, 256, 0, stream>>>(degO, degI, ns, nd, NN);

    // CSR build
    scan_reduce<<<NB, 256, 0, stream>>>(degI, bsum, NN);
    scan_bsums<<<1, 64, 0, stream>>>(bsum, NB);
    scan_final<<<NB, 256, 0, stream>>>(degI, bsum, rowptr, cursor, NN, NEDGE);
    scatter_kernel<<<(NEDGE + 255) / 256, 256, 0, stream>>>(src, dst, cursor, permSrc, NEDGE);

    // layer-0 gather payload: bf16(x * ns)
    convx_kernel<<<(NN * 32 + 255) / 256, 256, 0, stream>>>(x, ns, actB, NN);

    const int dims[5] = {128, 128, 128, 256, 256};
    const int nrowp = (NN + 127) / 128;
    const int nrowp8 = ((nrowp + 7) / 8) * 8;

    for (int l = 0; l < 4; l++) {
        int K = dims[l], Dout = dims[l + 1];   // agg runs at width K (input side)
        int logD = (Dout == 128) ? 7 : 8;
        int logCB = (Dout == 128) ? 1 : 2;
        int CB = Dout / 64;

        convw_kernel<<<((K << logD) + 255) / 256, 256, 0, stream>>>(W[l], Wth, Wtl, K, logD);

        // Rb = bf16( nd * agg(actB) )
        int ablocks = (NN + 3) / 4;
        if (K == 128)
            agg_kernel<128><<<ablocks, 256, 0, stream>>>(actB, rowptr, permSrc, nd, Rb, NN);
        else
            agg_kernel<256><<<ablocks, 256, 0, stream>>>(actB, rowptr, permSrc, nd, Rb, NN);

        // actB' = bf16( relu(Rb@W + b) * (l<3 ? ns : 1) )
        const float* post = (l < 3) ? ns : nullptr;
        gemm_mfma<<<nrowp8 * CB, 256, 0, stream>>>(Rb, Wth, Wtl, b[l], post, actB,
                                                   NN, K, Dout, logCB, nrowp);
    }

    classifier_kernel<<<(NN + 63) / 64, 256, 0, stream>>>(actB, Wc, bc, out, NN);
}

// Round 10
// 457.414 us; speedup vs baseline: 6.0036x; 1.1473x over previous
//
#include <hip/hip_runtime.h>
#include <cstdint>
#include <cstddef>

#define NN 100000
#define NEDGE 800000
#define NBUCK 196          // node buckets: id = node >> 9 (512 nodes per bucket)
#define RNG 512

typedef __attribute__((ext_vector_type(8))) short short8v;
typedef __attribute__((ext_vector_type(16))) float float16v;

__device__ inline ushort f2bf(float f) {
    uint32_t u = __float_as_uint(f);
    u += 0x7fff + ((u >> 16) & 1);   // round-to-nearest-even
    return (ushort)(u >> 16);
}
__device__ inline float bf2f(ushort h) { return __uint_as_float(((uint32_t)h) << 16); }
__device__ inline void split2(float a, ushort& h, ushort& l) {
    h = f2bf(a);
    l = f2bf(a - bf2f(h));
}

__device__ inline void gload16(const void* g, void* lds) {
    __builtin_amdgcn_global_load_lds(
        (const __attribute__((address_space(1))) void*)g,
        (__attribute__((address_space(3))) void*)lds, 16, 0, 0);
}

// ================= bucketed CSR build (replaces atomic deg/scan/scatter) =================

// A: coarse bucket counts via LDS histograms
__global__ __launch_bounds__(256) void binA(const int* __restrict__ src, const int* __restrict__ dst,
                                            int* __restrict__ dstBinCnt, int* __restrict__ srcBinCnt, int E) {
    __shared__ int hd[NBUCK], hs[NBUCK];
    for (int i = threadIdx.x; i < NBUCK; i += 256) { hd[i] = 0; hs[i] = 0; }
    __syncthreads();
    for (int i = blockIdx.x * 256 + threadIdx.x; i < E; i += gridDim.x * 256) {
        atomicAdd(&hs[src[i] >> 9], 1);
        atomicAdd(&hd[dst[i] >> 9], 1);
    }
    __syncthreads();
    for (int i = threadIdx.x; i < NBUCK; i += 256) {
        if (hd[i]) atomicAdd(&dstBinCnt[i], hd[i]);
        if (hs[i]) atomicAdd(&srcBinCnt[i], hs[i]);
    }
}

// B0: scan bucket counts -> bases + cursors
__global__ void binScan(const int* __restrict__ dstBinCnt, const int* __restrict__ srcBinCnt,
                        int* __restrict__ dstBase, int* __restrict__ srcBase,
                        int* __restrict__ dstCur, int* __restrict__ srcCur) {
    if (threadIdx.x == 0 && blockIdx.x == 0) {
        int a = 0;
        for (int i = 0; i < NBUCK; i++) { dstBase[i] = a; dstCur[i] = a; a += dstBinCnt[i]; }
        dstBase[NBUCK] = a;
        a = 0;
        for (int i = 0; i < NBUCK; i++) { srcBase[i] = a; srcCur[i] = a; a += srcBinCnt[i]; }
        srcBase[NBUCK] = a;
    }
}

// B: partition edges into dst-bucketed (src,dst) pairs and src-bucketed src ids
__global__ __launch_bounds__(256) void partition_kernel(
        const int* __restrict__ src, const int* __restrict__ dst,
        int* __restrict__ dstCur, int* __restrict__ srcCur,
        int2* __restrict__ pairBuck, int* __restrict__ srcBuck, int E) {
    __shared__ int cd[NBUCK], bd[NBUCK], cs[NBUCK], bs[NBUCK];
    const int CH = (E + gridDim.x - 1) / gridDim.x;
    const int lo = blockIdx.x * CH;
    const int hi = min(lo + CH, E);
    for (int i = threadIdx.x; i < NBUCK; i += 256) { cd[i] = 0; cs[i] = 0; }
    __syncthreads();
    for (int i = lo + threadIdx.x; i < hi; i += 256) {
        atomicAdd(&cd[dst[i] >> 9], 1);
        atomicAdd(&cs[src[i] >> 9], 1);
    }
    __syncthreads();
    for (int i = threadIdx.x; i < NBUCK; i += 256) {
        bd[i] = cd[i] ? atomicAdd(&dstCur[i], cd[i]) : 0;
        bs[i] = cs[i] ? atomicAdd(&srcCur[i], cs[i]) : 0;
        cd[i] = 0; cs[i] = 0;
    }
    __syncthreads();
    for (int i = lo + threadIdx.x; i < hi; i += 256) {
        int s = src[i], d = dst[i];
        int slot = atomicAdd(&cd[d >> 9], 1);
        pairBuck[bd[d >> 9] + slot] = make_int2(s, d);
        int slot2 = atomicAdd(&cs[s >> 9], 1);
        srcBuck[bs[s >> 9] + slot2] = s;
    }
}

// C1: per-bucket src histogram -> ns = 1/sqrt(max(outdeg,1))
__global__ __launch_bounds__(256) void srcHist(const int* __restrict__ srcBuck,
                                               const int* __restrict__ srcBase,
                                               float* __restrict__ ns, int n) {
    __shared__ int h[RNG];
    const int k = blockIdx.x;
    for (int i = threadIdx.x; i < RNG; i += 256) h[i] = 0;
    __syncthreads();
    const int lo = srcBase[k], hi = srcBase[k + 1];
    for (int i = lo + threadIdx.x; i < hi; i += 256)
        atomicAdd(&h[srcBuck[i] & (RNG - 1)], 1);
    __syncthreads();
    for (int i = threadIdx.x; i < RNG; i += 256) {
        int idx = k * RNG + i;
        if (idx < n) ns[idx] = 1.0f / sqrtf((float)max(h[i], 1));
    }
}

// C2: per-bucket dst histogram + scan -> rowptr, nd; then in-kernel CSR scatter
__global__ __launch_bounds__(256) void dstBuild(const int2* __restrict__ pairBuck,
                                                const int* __restrict__ dstBase,
                                                float* __restrict__ nd, int* __restrict__ rowptr,
                                                int* __restrict__ permSrc, int n) {
    __shared__ int h[RNG];
    __shared__ int tsum[256];
    const int k = blockIdx.x;
    const int t = threadIdx.x;
    for (int i = t; i < RNG; i += 256) h[i] = 0;
    __syncthreads();
    const int lo = dstBase[k], hi = dstBase[k + 1];
    for (int i = lo + t; i < hi; i += 256)
        atomicAdd(&h[pairBuck[i].y & (RNG - 1)], 1);
    __syncthreads();
    // exclusive scan of h[512]: 2 elems per thread
    int a0 = h[2 * t], a1 = h[2 * t + 1];
    tsum[t] = a0 + a1;
    __syncthreads();
    for (int off = 1; off < 256; off <<= 1) {
        int v = (t >= off) ? tsum[t - off] : 0;
        __syncthreads();
        tsum[t] += v;
        __syncthreads();
    }
    const int pre = lo + (t > 0 ? tsum[t - 1] : 0);
    const int r0 = pre, r1 = pre + a0;
    const int idx0 = k * RNG + 2 * t;
    if (idx0 <= n) rowptr[idx0] = r0;
    if (idx0 + 1 <= n) rowptr[idx0 + 1] = r1;
    if (idx0 < n) nd[idx0] = 1.0f / sqrtf((float)max(a0, 1));
    if (idx0 + 1 < n) nd[idx0 + 1] = 1.0f / sqrtf((float)max(a1, 1));
    h[2 * t] = r0;
    h[2 * t + 1] = r1;
    __syncthreads();
    // scatter: h[] now holds global cursors
    for (int i = lo + t; i < hi; i += 256) {
        int2 p = pairBuck[i];
        int pos = atomicAdd(&h[p.y & (RNG - 1)], 1);
        permSrc[pos] = p.x;
    }
}

// ================= converters =================

__global__ void convx_kernel(const float* __restrict__ x, const float* __restrict__ ns,
                             ushort* __restrict__ actB, int n) {
    int idx = blockIdx.x * blockDim.x + threadIdx.x;   // float4 units
    if (idx >= n * 32) return;
    int node = idx >> 5;
    int f0 = (idx & 31) * 4;
    float sc = ns[node];
    float4 v = *reinterpret_cast<const float4*>(x + (size_t)node * 128 + f0);
    ushort4 h;
    h.x = f2bf(v.x * sc);
    h.y = f2bf(v.y * sc);
    h.z = f2bf(v.z * sc);
    h.w = f2bf(v.w * sc);
    *reinterpret_cast<ushort4*>(actB + (size_t)node * 128 + f0) = h;
}

// all 4 layers' W -> transposed hi/lo in one launch
// layout: L0 [0,16384) K=128 logD=7 | L1 [16384,32768) | L2 [32768,65536) logD=8 | L3 [65536,131072) K=256
__global__ void convw_all(const float* __restrict__ W0, const float* __restrict__ W1,
                          const float* __restrict__ W2, const float* __restrict__ W3,
                          ushort* __restrict__ Wth, ushort* __restrict__ Wtl) {
    int idx = blockIdx.x * blockDim.x + threadIdx.x;
    if (idx >= 131072) return;
    const float* W; int K, logD, base;
    if (idx < 16384)      { W = W0; K = 128; logD = 7; base = 0; }
    else if (idx < 32768) { W = W1; K = 128; logD = 7; base = 16384; }
    else if (idx < 65536) { W = W2; K = 128; logD = 8; base = 32768; }
    else                  { W = W3; K = 256; logD = 8; base = 65536; }
    int loc = idx - base;
    int k = loc >> logD, d = loc & ((1 << logD) - 1);
    ushort h, l;
    split2(W[loc], h, l);
    Wth[base + d * K + k] = h;
    Wtl[base + d * K + k] = l;
}

// ================= CSR aggregation: 16B gather loads, edge-group MLP =================
// Rb[node] = bf16( nd[node] * sum_{e in CSR(node)} act[src[e]] )

__device__ inline void accum8(float* a, uint4 v) {
    a[0] += __uint_as_float(v.x << 16);
    a[1] += __uint_as_float(v.x & 0xffff0000u);
    a[2] += __uint_as_float(v.y << 16);
    a[3] += __uint_as_float(v.y & 0xffff0000u);
    a[4] += __uint_as_float(v.z << 16);
    a[5] += __uint_as_float(v.z & 0xffff0000u);
    a[6] += __uint_as_float(v.w << 16);
    a[7] += __uint_as_float(v.w & 0xffff0000u);
}

template<int D>
__global__ __launch_bounds__(256) void agg_kernel(
        const ushort* __restrict__ act, const int* __restrict__ rowptr,
        const int* __restrict__ permSrc, const float* __restrict__ nd,
        ushort* __restrict__ Rb, int n) {
    int node = blockIdx.x * 4 + (threadIdx.x >> 6);
    if (node >= n) return;
    int lane = threadIdx.x & 63;
    constexpr int GROUPS = (D == 256) ? 2 : 4;   // edge slices per wave
    constexpr int GL = 64 / GROUPS;              // lanes per slice (32 / 16)
    const int g  = lane / GL;
    const int gl = lane % GL;
    const int f0 = gl * 8;                       // 8 bf16 per lane (16B)
    float a[8] = {0.f,0.f,0.f,0.f,0.f,0.f,0.f,0.f};
    int r0 = rowptr[node], r1 = rowptr[node + 1];

    int e = r0 + g;
    for (; e + 3 * GROUPS < r1; e += 4 * GROUPS) {
        int s0 = permSrc[e];
        int s1 = permSrc[e + GROUPS];
        int s2 = permSrc[e + 2 * GROUPS];
        int s3 = permSrc[e + 3 * GROUPS];
        uint4 v0 = *reinterpret_cast<const uint4*>(act + (size_t)s0 * D + f0);
        uint4 v1 = *reinterpret_cast<const uint4*>(act + (size_t)s1 * D + f0);
        uint4 v2 = *reinterpret_cast<const uint4*>(act + (size_t)s2 * D + f0);
        uint4 v3 = *reinterpret_cast<const uint4*>(act + (size_t)s3 * D + f0);
        accum8(a, v0); accum8(a, v1); accum8(a, v2); accum8(a, v3);
    }
    for (; e < r1; e += GROUPS) {
        int s = permSrc[e];
        accum8(a, *reinterpret_cast<const uint4*>(act + (size_t)s * D + f0));
    }

    #pragma unroll
    for (int j = 0; j < 8; j++) {
        if constexpr (GROUPS == 4) a[j] += __shfl_xor(a[j], 16);
        a[j] += __shfl_xor(a[j], 32);
    }

    if (g == 0) {
        float sc = nd[node];
        union { ushort u[8]; uint4 v; } H;
        #pragma unroll
        for (int j = 0; j < 8; j++) H.u[j] = f2bf(a[j] * sc);
        *reinterpret_cast<uint4*>(Rb + (size_t)node * D + f0) = H.v;
    }
}

// ================= MFMA GEMM with fused epilogue =================
// Cb[n][Dout] = bf16( relu( A@(Bhi+Blo)^T + bias ) * (post ? post[row] : 1) )

__global__ __launch_bounds__(256) void gemm_mfma(
        const ushort* __restrict__ A,
        const ushort* __restrict__ Bhi, const ushort* __restrict__ Blo,
        const float* __restrict__ bias, const float* __restrict__ post,
        ushort* __restrict__ Cb, int n, int K, int Dout, int logCB, int nrowp) {
    __shared__ __align__(16) ushort sA[128][64];
    __shared__ __align__(16) ushort sBh[64][64];
    __shared__ __align__(16) ushort sBl[64][64];
    const int tid = threadIdx.x;
    const int lane = tid & 63;
    const int wid = tid >> 6;
    const int l31 = lane & 31;
    const int kg = lane >> 5;         // k-group (0/1)

    // XCD co-location decode
    const int bid = blockIdx.x;
    const int xcd = bid & 7;
    const int t = bid >> 3;
    const int cb2 = t & ((1 << logCB) - 1);
    const int rp = (t >> logCB) * 8 + xcd;
    if (rp >= nrowp) return;
    const int row0 = rp * 128;
    const int col0 = cb2 * 64;

    // precompute per-issue global bases (k0-invariant) and uniform LDS bases
    const ushort* gA[4];
    char* lA[4];
    #pragma unroll
    for (int i = 0; i < 4; i++) {
        int slot = i * 256 + wid * 64 + lane;
        int r = slot >> 3, ch = slot & 7;
        int gch = ch ^ (r & 7);
        int row = row0 + r; if (row >= n) row = n - 1;   // clamp: dup rows feed discarded C rows
        gA[i] = A + (size_t)row * K + gch * 8;
        lA[i] = (char*)&sA[0][0] + (size_t)(i * 256 + wid * 64) * 16;  // uniform per wave
    }
    const ushort* gBh[2]; const ushort* gBl[2];
    char* lB[2];
    #pragma unroll
    for (int i = 0; i < 2; i++) {
        int slot = i * 256 + wid * 64 + lane;
        int r = slot >> 3, ch = slot & 7;
        int gch = ch ^ (r & 7);
        gBh[i] = Bhi + (size_t)(col0 + r) * K + gch * 8;
        gBl[i] = Blo + (size_t)(col0 + r) * K + gch * 8;
        lB[i] = (char*)&sBh[0][0] + (size_t)(i * 256 + wid * 64) * 16;
    }
    const size_t lblo = (char*)&sBl[0][0] - (char*)&sBh[0][0];

    float16v acc0 = {0.f,0.f,0.f,0.f,0.f,0.f,0.f,0.f,0.f,0.f,0.f,0.f,0.f,0.f,0.f,0.f};
    float16v acc1 = {0.f,0.f,0.f,0.f,0.f,0.f,0.f,0.f,0.f,0.f,0.f,0.f,0.f,0.f,0.f,0.f};

    for (int k0 = 0; k0 < K; k0 += 64) {
        #pragma unroll
        for (int i = 0; i < 4; i++) gload16(gA[i] + k0, lA[i]);
        #pragma unroll
        for (int i = 0; i < 2; i++) {
            gload16(gBh[i] + k0, lB[i]);
            gload16(gBl[i] + k0, lB[i] + lblo);
        }
        __syncthreads();

        #pragma unroll
        for (int ks = 0; ks < 4; ks++) {
            const int gw = ks * 2 + kg;          // wanted global chunk
            const int rA = wid * 32 + l31;
            const int rB0 = l31, rB1 = 32 + l31;
            short8v a = *reinterpret_cast<const short8v*>(&sA[rA][(gw ^ (rA & 7)) * 8]);
            short8v bh0 = *reinterpret_cast<const short8v*>(&sBh[rB0][(gw ^ (rB0 & 7)) * 8]);
            short8v bl0 = *reinterpret_cast<const short8v*>(&sBl[rB0][(gw ^ (rB0 & 7)) * 8]);
            short8v bh1 = *reinterpret_cast<const short8v*>(&sBh[rB1][(gw ^ (rB1 & 7)) * 8]);
            short8v bl1 = *reinterpret_cast<const short8v*>(&sBl[rB1][(gw ^ (rB1 & 7)) * 8]);
            acc0 = __builtin_amdgcn_mfma_f32_32x32x16_bf16(a, bh0, acc0, 0, 0, 0);
            acc1 = __builtin_amdgcn_mfma_f32_32x32x16_bf16(a, bh1, acc1, 0, 0, 0);
            acc0 = __builtin_amdgcn_mfma_f32_32x32x16_bf16(a, bl0, acc0, 0, 0, 0);
            acc1 = __builtin_amdgcn_mfma_f32_32x32x16_bf16(a, bl1, acc1, 0, 0, 0);
        }
        __syncthreads();
    }

    // epilogue: C/D layout: col = lane&31, row = (r&3) + 8*(r>>2) + 4*(lane>>5)
    const int rbase = row0 + wid * 32;
    #pragma unroll
    for (int cb = 0; cb < 2; cb++) {
        const int colg = col0 + cb * 32 + l31;
        const float bcol = bias[colg];
        const float16v& acc = cb ? acc1 : acc0;
        #pragma unroll
        for (int r = 0; r < 16; r++) {
            int rowg = rbase + (r & 3) + 8 * (r >> 2) + 4 * kg;
            if (rowg < n) {
                float v = fmaxf(acc[r] + bcol, 0.0f);
                if (post) v *= post[rowg];
                Cb[(size_t)rowg * Dout + colg] = f2bf(v);
            }
        }
    }
}

// ================= classifier: out = h @ Wc + bc  (h bf16, K=256, Dout=4) =================

__global__ __launch_bounds__(256) void classifier_kernel(
        const ushort* __restrict__ h, const float* __restrict__ Wc,
        const float* __restrict__ bc, float* __restrict__ out, int n) {
    __shared__ float Ws[256 * 4];
    int tid = threadIdx.x;
    for (int i = tid; i < 1024; i += 256) Ws[i] = Wc[i];
    __syncthreads();
    int node = blockIdx.x * 64 + (tid >> 2);
    int c = tid & 3;
    if (node < n) {
        float sum = bc[c];
        const ushort* hr = h + (size_t)node * 256;
        #pragma unroll
        for (int k0 = 0; k0 < 256; k0 += 8) {
            uint4 pk = *reinterpret_cast<const uint4*>(hr + k0);
            sum = fmaf(bf2f((ushort)(pk.x & 0xffff)), Ws[(k0 + 0) * 4 + c], sum);
            sum = fmaf(bf2f((ushort)(pk.x >> 16)),    Ws[(k0 + 1) * 4 + c], sum);
            sum = fmaf(bf2f((ushort)(pk.y & 0xffff)), Ws[(k0 + 2) * 4 + c], sum);
            sum = fmaf(bf2f((ushort)(pk.y >> 16)),    Ws[(k0 + 3) * 4 + c], sum);
            sum = fmaf(bf2f((ushort)(pk.z & 0xffff)), Ws[(k0 + 4) * 4 + c], sum);
            sum = fmaf(bf2f((ushort)(pk.z >> 16)),    Ws[(k0 + 5) * 4 + c], sum);
            sum = fmaf(bf2f((ushort)(pk.w & 0xffff)), Ws[(k0 + 6) * 4 + c], sum);
            sum = fmaf(bf2f((ushort)(pk.w >> 16)),    Ws[(k0 + 7) * 4 + c], sum);
        }
        out[(size_t)node * 4 + c] = sum;
    }
}

// ================= launch =================

extern "C" void kernel_launch(void* const* d_in, const int* in_sizes, int n_in,
                              void* d_out, int out_size, void* d_ws, size_t ws_size,
                              hipStream_t stream) {
    const float* x   = (const float*)d_in[0];
    const int*   src = (const int*)d_in[1];
    const int*   dst = (const int*)d_in[2];
    const float* W0 = (const float*)d_in[3];
    const float* b0 = (const float*)d_in[4];
    const float* W1 = (const float*)d_in[5];
    const float* b1 = (const float*)d_in[6];
    const float* W2 = (const float*)d_in[7];
    const float* b2 = (const float*)d_in[8];
    const float* W3 = (const float*)d_in[9];
    const float* b3 = (const float*)d_in[10];
    const float* Wc = (const float*)d_in[11];
    const float* bc = (const float*)d_in[12];
    const float* b[4] = {b0, b1, b2, b3};
    float* out = (float*)d_out;

    // ---- workspace layout ----
    ushort* actB = (ushort*)d_ws;                        // N*256 ushort
    ushort* Rb   = actB + (size_t)NN * 256;              // N*256 ushort
    float*  ns   = (float*)(Rb + (size_t)NN * 256);      // N f32
    float*  nd   = ns + NN;                              // N f32
    ushort* Wth  = (ushort*)(nd + NN);                   // 131072 ushort (all layers, transposed hi)
    ushort* Wtl  = Wth + 131072;                         // 131072 ushort (lo)
    int*    rowptr  = (int*)(Wtl + 131072);              // N+1 int
    int*    permSrc = rowptr + (NN + 1);                 // E int
    int*    dstBinCnt = permSrc + NEDGE;                 // NBUCK
    int*    srcBinCnt = dstBinCnt + NBUCK;               // NBUCK
    int*    dstBase   = srcBinCnt + NBUCK;               // NBUCK+1
    int*    srcBase   = dstBase + NBUCK + 1;             // NBUCK+1
    int*    dstCur    = srcBase + NBUCK + 1;             // NBUCK
    int*    srcCur    = dstCur + NBUCK;                  // NBUCK
    // transient (setup only) aliased into Rb: consumed before agg L0 writes Rb
    int2*   pairBuck = (int2*)Rb;                        // E int2 (6.4 MB)
    int*    srcBuck  = (int*)(pairBuck + NEDGE);         // E int  (3.2 MB)
    (void)in_sizes; (void)n_in; (void)out_size; (void)ws_size;

    // ---- bucketed CSR build ----
    hipMemsetAsync(dstBinCnt, 0, 2 * NBUCK * sizeof(int), stream);
    binA<<<256, 256, 0, stream>>>(src, dst, dstBinCnt, srcBinCnt, NEDGE);
    binScan<<<1, 64, 0, stream>>>(dstBinCnt, srcBinCnt, dstBase, srcBase, dstCur, srcCur);
    partition_kernel<<<256, 256, 0, stream>>>(src, dst, dstCur, srcCur, pairBuck, srcBuck, NEDGE);
    convw_all<<<512, 256, 0, stream>>>(W0, W1, W2, W3, Wth, Wtl);   // independent; overlaps tail
    srcHist<<<NBUCK, 256, 0, stream>>>(srcBuck, srcBase, ns, NN);
    dstBuild<<<NBUCK, 256, 0, stream>>>(pairBuck, dstBase, nd, rowptr, permSrc, NN);

    // layer-0 gather payload: bf16(x * ns)
    convx_kernel<<<(NN * 32 + 255) / 256, 256, 0, stream>>>(x, ns, actB, NN);

    const int dims[5] = {128, 128, 128, 256, 256};
    const int woff[4] = {0, 16384, 32768, 65536};
    const int nrowp = (NN + 127) / 128;
    const int nrowp8 = ((nrowp + 7) / 8) * 8;

    for (int l = 0; l < 4; l++) {
        int K = dims[l], Dout = dims[l + 1];   // agg runs at width K (input side)
        int logCB = (Dout == 128) ? 1 : 2;
        int CB = Dout / 64;

        // Rb = bf16( nd * agg(actB) )
        int ablocks = (NN + 3) / 4;
        if (K == 128)
            agg_kernel<128><<<ablocks, 256, 0, stream>>>(actB, rowptr, permSrc, nd, Rb, NN);
        else
            agg_kernel<256><<<ablocks, 256, 0, stream>>>(actB, rowptr, permSrc, nd, Rb, NN);

        // actB' = bf16( relu(Rb@W + b) * (l<3 ? ns : 1) )
        const float* post = (l < 3) ? ns : nullptr;
        gemm_mfma<<<nrowp8 * CB, 256, 0, stream>>>(Rb, Wth + woff[l], Wtl + woff[l], b[l], post,
                                                   actB, NN, K, Dout, logCB, nrowp);
    }

    classifier_kernel<<<(NN + 63) / 64, 256, 0, stream>>>(actB, Wc, bc, out, NN);
}